// Round 8
// baseline (659.151 us; speedup 1.0000x reference)
//
#include <hip/hip_runtime.h>
#include <cstdint>
#include <cstddef>

typedef __attribute__((ext_vector_type(4))) float  f32x4;
typedef __attribute__((ext_vector_type(4))) int    i32x4;
typedef __attribute__((ext_vector_type(8))) short  s16x8;
typedef __attribute__((ext_vector_type(4))) short  s16x4;
typedef __attribute__((ext_vector_type(8))) __bf16 bf16x8;

struct Ptr4 { const float* p[4]; };

#define DEV __device__ __forceinline__

DEV unsigned short f2bf_u(float x) {
  unsigned u = __builtin_bit_cast(unsigned, x);
  u += 0x7fffu + ((u >> 16) & 1u);
  return (unsigned short)(u >> 16);
}
DEV float bfu2f(unsigned short u) {
  return __builtin_bit_cast(float, ((unsigned)u) << 16);
}
DEV bf16x8 ld_frag(const unsigned short* p) {
  s16x8 v = *(const s16x8*)p;
  return __builtin_bit_cast(bf16x8, v);
}
DEV f32x4 mfma16(bf16x8 a, bf16x8 b, f32x4 c) {
  return __builtin_amdgcn_mfma_f32_16x16x32_bf16(a, b, c, 0, 0, 0);
}
// async global->LDS, 16B per lane; LDS dest = wave-uniform base + lane*16
DEV void gload_lds16(const unsigned short* g, unsigned short* l) {
  __builtin_amdgcn_global_load_lds(
      (const __attribute__((address_space(1))) unsigned int*)g,
      (__attribute__((address_space(3))) unsigned int*)l, 16, 0, 0);
}
// XCD-chunked bijective block-id swizzle (requires nwg % 8 == 0).
// KEPT ONLY for attention (4 bh x 1MB K/V per XCD = L2-fit). REMOVED from
// GEMMs: r5-vs-r7 A/B on the split GEMM showed swizzle = -8% when operands
// are L3-fit (192.5 -> 207.8 us despite FETCH 292 -> 236 MB).
DEV int xcd_swizzle(int bid, int nwg) {
  const int q8 = nwg >> 3;
  return (bid & 7) * q8 + (bid >> 3);
}

// ---------------------------------------------------------------------------
// |W| row sums (one block per row, deterministic)
// ---------------------------------------------------------------------------
__global__ __launch_bounds__(256)
void k_rowsum(Ptr4 Ws, float* __restrict__ rowsums)
{
  const int row = blockIdx.x, mat = blockIdx.y, tid = threadIdx.x;
  const float* W = Ws.p[mat] + (size_t)row * 2048;
  float s = 0.f;
  #pragma unroll
  for (int p = 0; p < 2; ++p) {
    f32x4 v = *(const f32x4*)(W + p * 1024 + tid * 4);
    s += fabsf(v[0]) + fabsf(v[1]) + fabsf(v[2]) + fabsf(v[3]);
  }
  #pragma unroll
  for (int off = 1; off < 64; off <<= 1) s += __shfl_xor(s, off);
  __shared__ float red[4];
  if ((tid & 63) == 0) red[tid >> 6] = s;
  __syncthreads();
  if (tid == 0) rowsums[mat * 2048 + row] = red[0] + red[1] + red[2] + red[3];
}

// |W| column sums: partial over 64-row stripes, then reduce (no atomics)
__global__ __launch_bounds__(256)
void k_colsum_part(Ptr4 Ws, float* __restrict__ part)
{
  const int c = blockIdx.x * 256 + threadIdx.x;
  const int r0 = blockIdx.y * 64;
  const int mat = blockIdx.z;
  const float* W = Ws.p[mat];
  float s = 0.f;
  for (int rr = 0; rr < 64; ++rr) s += fabsf(W[(size_t)(r0 + rr) * 2048 + c]);
  part[((size_t)mat * 32 + blockIdx.y) * 2048 + c] = s;
}
__global__ __launch_bounds__(256)
void k_colsum_red(const float* __restrict__ part, float* __restrict__ colsums)
{
  const int gid = blockIdx.x * 256 + threadIdx.x;   // 4*2048
  const int mat = gid >> 11, c = gid & 2047;
  float s = 0.f;
  #pragma unroll
  for (int j = 0; j < 32; ++j) s += part[((size_t)mat * 32 + j) * 2048 + c];
  colsums[gid] = s;
}

// metric[r,c] = |W|*(1/colsum[c] + 1/rowsum[r]) * sqrt(scaler[c]) ; hi/lo bf16 split
__global__ __launch_bounds__(256)
void k_metric(Ptr4 Ws, Ptr4 Ss, const float* __restrict__ rowsums,
              const float* __restrict__ colsums,
              unsigned short* __restrict__ mhi, unsigned short* __restrict__ mlo)
{
  const size_t idx4 = ((size_t)blockIdx.x * 256 + threadIdx.x) * 4;
  const int row = (int)(idx4 >> 11);
  const int c = (int)(idx4 & 2047);
  const int mat = row >> 11, rl = row & 2047;
  const float rs = rowsums[mat * 2048 + rl];
  f32x4 w  = *(const f32x4*)(Ws.p[mat] + (size_t)rl * 2048 + c);
  f32x4 cs = *(const f32x4*)(colsums + mat * 2048 + c);
  f32x4 sv = *(const f32x4*)(Ss.p[mat] + c);
  s16x4 hv, lv;
  #pragma unroll
  for (int j = 0; j < 4; ++j) {
    const float a = fabsf(w[j]);
    const float m = (a / cs[j] + a / rs) * sqrtf(sv[j]);
    const unsigned short hb = f2bf_u(m);
    hv[j] = (short)hb;
    lv[j] = (short)f2bf_u(m - bfu2f(hb));
  }
  *(s16x4*)(mhi + idx4) = hv;
  *(s16x4*)(mlo + idx4) = lv;
}

// perm -> permT hi/lo bf16 (tiled transpose) + fused plain bf16 cast
__global__ __launch_bounds__(256)
void k_perm_prep(const float* __restrict__ pq, const float* __restrict__ po,
                 unsigned short* __restrict__ thi_q, unsigned short* __restrict__ tlo_q,
                 unsigned short* __restrict__ thi_o, unsigned short* __restrict__ tlo_o,
                 unsigned short* __restrict__ pb_q, unsigned short* __restrict__ pb_o)
{
  __shared__ float T[64 * 65];
  const int which = blockIdx.z;
  const float* src = which ? po : pq;
  unsigned short* thi = which ? thi_o : thi_q;
  unsigned short* tlo = which ? tlo_o : tlo_q;
  unsigned short* pb  = which ? pb_o : pb_q;
  const int rb = blockIdx.y * 64, cb = blockIdx.x * 64, tid = threadIdx.x;
  #pragma unroll
  for (int i = 0; i < 4; ++i) {
    const int cc = i * 256 + tid;
    const int rowl = cc >> 4, c4 = (cc & 15) * 4;
    f32x4 v = *(const f32x4*)(src + (size_t)(rb + rowl) * 2048 + cb + c4);
    s16x4 pc;
    #pragma unroll
    for (int j = 0; j < 4; ++j) {
      T[rowl * 65 + c4 + j] = v[j];
      pc[j] = (short)f2bf_u(v[j]);
    }
    *(s16x4*)(pb + (size_t)(rb + rowl) * 2048 + cb + c4) = pc;
  }
  __syncthreads();
  #pragma unroll
  for (int i = 0; i < 4; ++i) {
    const int cc = i * 256 + tid;
    const int rowt = cc >> 4, c4 = (cc & 15) * 4;
    s16x4 hh, ll;
    #pragma unroll
    for (int j = 0; j < 4; ++j) {
      const float v = T[(c4 + j) * 65 + rowt];
      const unsigned short hb = f2bf_u(v);
      hh[j] = (short)hb;
      ll[j] = (short)f2bf_u(v - bfu2f(hb));
    }
    const size_t off = (size_t)(cb + rowt) * 2048 + rb + c4;
    *(s16x4*)(thi + off) = hh;
    *(s16x4*)(tlo + off) = ll;
  }
}

// plain f32 -> bf16 cast (8 elems/thread)
__global__ __launch_bounds__(256)
void k_cast_bf(const float* __restrict__ src, unsigned short* __restrict__ dst)
{
  const size_t i = ((size_t)blockIdx.x * 256 + threadIdx.x) * 8;
  f32x4 a = *(const f32x4*)(src + i);
  f32x4 b = *(const f32x4*)(src + i + 4);
  s16x8 o;
  #pragma unroll
  for (int j = 0; j < 4; ++j) o[j] = (short)f2bf_u(a[j]);
  #pragma unroll
  for (int j = 0; j < 4; ++j) o[4 + j] = (short)f2bf_u(b[j]);
  *(s16x8*)(dst + i) = o;
}

// RoPE tables [2048][64]
__global__ __launch_bounds__(256)
void k_rope_tab(float* __restrict__ ct, float* __restrict__ st)
{
  const int gid = blockIdx.x * 256 + threadIdx.x;
  const int s = gid >> 6, i = gid & 63;
  const float ex = (float)(2 * i) / 128.f;
  const float inv = 1.f / powf(10000.f, ex);
  const float f = (float)s * inv;
  ct[gid] = cosf(f);
  st[gid] = sinf(f);
}

// y_qkv [4096][6144] -> q,k head-major [2][16][2048][128] with RoPE.
// Vectorized: one thread = 8 consecutive d (s16x8 loads; partner chunk d8^8).
__global__ __launch_bounds__(256)
void k_rope_reshape(const unsigned short* __restrict__ yqkv, const int* __restrict__ pos,
                    const float* __restrict__ ct, const float* __restrict__ st,
                    unsigned short* __restrict__ qo, unsigned short* __restrict__ ko)
{
  const int gid = blockIdx.x * 256 + threadIdx.x;   // 2*16*2048*16 chunks
  const int d8 = gid & 15;
  const int s = (gid >> 4) & 2047;
  const int h = (gid >> 15) & 15;
  const int b = gid >> 19;
  const int t = b * 2048 + s;
  const int p = pos[t];
  const size_t yb = (size_t)t * 6144 + h * 128;
  s16x8 qv = *(const s16x8*)(yqkv + yb + d8 * 8);
  s16x8 qp = *(const s16x8*)(yqkv + yb + (d8 ^ 8) * 8);
  s16x8 kv = *(const s16x8*)(yqkv + yb + 2048 + d8 * 8);
  s16x8 kp = *(const s16x8*)(yqkv + yb + 2048 + (d8 ^ 8) * 8);
  const int dh0 = (d8 & 7) * 8;
  const float sgn = (d8 < 8) ? -1.f : 1.f;
  s16x8 qo8, ko8;
  #pragma unroll
  for (int j = 0; j < 8; ++j) {
    const float cv = ct[p * 64 + dh0 + j];
    const float sv = st[p * 64 + dh0 + j];
    const float q0 = bfu2f((unsigned short)qv[j]);
    const float k0 = bfu2f((unsigned short)kv[j]);
    const float q1 = sgn * bfu2f((unsigned short)qp[j]);
    const float k1 = sgn * bfu2f((unsigned short)kp[j]);
    qo8[j] = (short)f2bf_u(q0 * cv + q1 * sv);
    ko8[j] = (short)f2bf_u(k0 * cv + k1 * sv);
  }
  const size_t o = ((size_t)(b * 16 + h) * 2048 + s) * 128 + d8 * 8;
  *(s16x8*)(qo + o) = qo8;
  *(s16x8*)(ko + o) = ko8;
}

// y_qkv v-part -> Vt global [2][16][128][2048] (LDS-tiled transpose)
__global__ __launch_bounds__(256)
void k_vtrans(const unsigned short* __restrict__ yqkv, unsigned short* __restrict__ vt)
{
  __shared__ float T[64 * 129];
  const int st = blockIdx.x, bh = blockIdx.y, tid = threadIdx.x;
  const int b = bh >> 4, h = bh & 15;
  #pragma unroll
  for (int i = 0; i < 4; ++i) {
    const int c = i * 256 + tid;           // 0..1023
    const int sl = c >> 4, d8 = (c & 15) * 8;
    s16x8 v = *(const s16x8*)(yqkv + (size_t)(b * 2048 + st * 64 + sl) * 6144 + 4096 + h * 128 + d8);
    #pragma unroll
    for (int j = 0; j < 8; ++j) T[sl * 129 + d8 + j] = bfu2f((unsigned short)v[j]);
  }
  __syncthreads();
  #pragma unroll
  for (int i = 0; i < 4; ++i) {
    const int c = i * 256 + tid;
    const int d = c >> 3, s8 = (c & 7) * 8;
    s16x8 o;
    #pragma unroll
    for (int j = 0; j < 8; ++j) o[j] = (short)f2bf_u(T[(s8 + j) * 129 + d]);
    *(s16x8*)(vt + ((size_t)bh * 128 + d) * 2048 + st * 64 + s8) = o;
  }
}

// ---------------------------------------------------------------------------
// Generic bf16 MFMA GEMM, C[M,N] = A[M,K] @ B[N,K]^T, 128x128 tile, BK=32.
// Linear block order (XCD swizzle removed: r5-vs-r7 A/B showed -8% on the
// L3-fit GEMM operands). Double-buffered LDS for BOTH paths, ONE barrier per
// K-step; prefetch for kt+1 issued right after the barrier so loads cover
// frag ds_reads + the MFMA block (~450+ cy vs ~230 before on SPLIT).
// SPLIT LDS: hi/lo planes x 2 bufs = 64KB total (occupancy already 2 blk/CU).
// Staging via global_load_lds (16B/lane, linear LDS dest); global source is
// pre-swizzled (chunk ^= (row>>1)&3, conflict-free 2-way) and ds_read applies
// the same XOR (rule #21: both sides, same involution).
// MODE 0: Cf = acc (f32).
// MODE 1: Cb = bf16(acc * aux.p[row>>11][row&2047, col]).
// MODE 2: Cb = bf16(acc + aux.p[col>>11][col&2047]).
// MODE 3: fused top-2-of-4 over col blocks -> Cb in {bf16 1.0, 0.0}.
// SPLIT: A,B given as hi/lo bf16 pairs; acc = Al*Bh + Ah*Bl + Ah*Bh.
// ---------------------------------------------------------------------------
template<int MODE, int SPLIT>
__global__ __launch_bounds__(256)
void gemm_bt(const unsigned short* __restrict__ Ahi, const unsigned short* __restrict__ Alo,
             const unsigned short* __restrict__ Bhi_1, const unsigned short* __restrict__ Blo_1,
             const unsigned short* __restrict__ Bhi_2, const unsigned short* __restrict__ Blo_2,
             int bswitch,
             float* __restrict__ Cf, unsigned short* __restrict__ Cb,
             Ptr4 aux, int M, int N, int K)
{
  constexpr int LO = 2 * 4096;   // lo-plane offset (elems) when SPLIT
  __shared__ alignas(16) unsigned short As[(SPLIT ? 4 : 2) * 4096];
  __shared__ alignas(16) unsigned short Bs[(SPLIT ? 4 : 2) * 4096];
  const int tid = threadIdx.x;
  const int lane = tid & 63, wid = tid >> 6;
  const int wm = wid >> 1, wn = wid & 1;
  const int r = lane & 15, g = lane >> 4;
  const int mbase = blockIdx.y * 128;
  const int nbase = blockIdx.x * 128;
  const int KT = K >> 5;
  (void)M;
  const unsigned short* Bhi = (mbase >= bswitch) ? Bhi_2 : Bhi_1;
  const unsigned short* Blo = (mbase >= bswitch) ? Blo_2 : Blo_1;

  const f32x4 zero = {0.f, 0.f, 0.f, 0.f};
  f32x4 acc[4][4];
  #pragma unroll
  for (int i = 0; i < 4; ++i) {
    #pragma unroll
    for (int j = 0; j < 4; ++j) acc[i][j] = zero;
  }

  // staging geometry: wave wid covers rows [wid*32, wid*32+32), 2 issues of
  // 16 rows (1KB each). Lane: row_local = lane>>2, chunk = lane&3 (16B).
  const int srl = lane >> 2;
  const int sch = lane & 3;

  auto issue_tile = [&](int kt, int buf) {
    const size_t kb = (size_t)kt * 32;
    #pragma unroll
    for (int i = 0; i < 2; ++i) {
      const int rbase = wid * 32 + i * 16;
      const int rloc = rbase + srl;
      const int sc = ((sch ^ ((rloc >> 1) & 3)) << 3);   // pre-swizzled source
      const size_t ga = (size_t)(mbase + rloc) * K + kb + sc;
      const size_t gb = (size_t)(nbase + rloc) * K + kb + sc;
      gload_lds16(Ahi + ga, &As[buf * 4096 + rbase * 32]);  // wave-uniform base
      gload_lds16(Bhi + gb, &Bs[buf * 4096 + rbase * 32]);
      if (SPLIT) {
        gload_lds16(Alo + ga, &As[LO + buf * 4096 + rbase * 32]);
        gload_lds16(Blo + gb, &Bs[LO + buf * 4096 + rbase * 32]);
      }
    }
  };

  issue_tile(0, 0);
  int cur = 0;
  for (int kt = 0; kt < KT; ++kt) {
    __syncthreads();   // buf[cur] staged (vmcnt drained); prior readers of
                       // buf[cur^1] done (lgkmcnt drained before barrier)
    if (kt + 1 < KT) issue_tile(kt + 1, cur ^ 1);  // covers ds_read + MFMA

    bf16x8 ah[4], bfr[4];
    #pragma unroll
    for (int mi = 0; mi < 4; ++mi) {
      const int arow = wm * 64 + mi * 16 + r;
      ah[mi] = ld_frag(&As[cur * 4096 + arow * 32 + ((g ^ ((arow >> 1) & 3)) << 3)]);
    }
    #pragma unroll
    for (int ni = 0; ni < 4; ++ni) {
      const int brow = wn * 64 + ni * 16 + r;
      bfr[ni] = ld_frag(&Bs[cur * 4096 + brow * 32 + ((g ^ ((brow >> 1) & 3)) << 3)]);
    }
    if (SPLIT) {
      bf16x8 al[4], bl[4];
      #pragma unroll
      for (int mi = 0; mi < 4; ++mi) {
        const int arow = wm * 64 + mi * 16 + r;
        al[mi] = ld_frag(&As[LO + cur * 4096 + arow * 32 + ((g ^ ((arow >> 1) & 3)) << 3)]);
      }
      #pragma unroll
      for (int ni = 0; ni < 4; ++ni) {
        const int brow = wn * 64 + ni * 16 + r;
        bl[ni] = ld_frag(&Bs[LO + cur * 4096 + brow * 32 + ((g ^ ((brow >> 1) & 3)) << 3)]);
      }
      #pragma unroll
      for (int mi = 0; mi < 4; ++mi) {
        #pragma unroll
        for (int ni = 0; ni < 4; ++ni) {
          acc[mi][ni] = mfma16(al[mi], bfr[ni], acc[mi][ni]);
          acc[mi][ni] = mfma16(ah[mi], bl[ni], acc[mi][ni]);
          acc[mi][ni] = mfma16(ah[mi], bfr[ni], acc[mi][ni]);
        }
      }
    } else {
      #pragma unroll
      for (int mi = 0; mi < 4; ++mi) {
        #pragma unroll
        for (int ni = 0; ni < 4; ++ni)
          acc[mi][ni] = mfma16(ah[mi], bfr[ni], acc[mi][ni]);
      }
    }
    cur ^= 1;
  }

  #pragma unroll
  for (int mi = 0; mi < 4; ++mi) {
    #pragma unroll
    for (int ni = 0; ni < 4; ++ni) {
      const int row0 = mbase + wm * 64 + mi * 16 + g * 4;
      const int col  = nbase + wn * 64 + ni * 16 + r;
      if (MODE == 0) {
        #pragma unroll
        for (int e = 0; e < 4; ++e)
          Cf[(size_t)(row0 + e) * N + col] = acc[mi][ni][e];
      } else if (MODE == 1) {
        const float* wsrc = aux.p[row0 >> 11];
        #pragma unroll
        for (int e = 0; e < 4; ++e) {
          const float mval = wsrc[(size_t)((row0 + e) & 2047) * 2048 + col];
          Cb[(size_t)(row0 + e) * N + col] = f2bf_u(acc[mi][ni][e] * mval);
        }
      } else if (MODE == 2) {
        const float* bp = aux.p[col >> 11];
        const float bb = bp[col & 2047];
        #pragma unroll
        for (int e = 0; e < 4; ++e)
          Cb[(size_t)(row0 + e) * N + col] = f2bf_u(acc[mi][ni][e] + bb);
      } else {
        // MODE 3: top-2-of-4 across the 4-col block; partners live in lanes
        // r^1, r^2, r^3 (same g). Rank by (value desc, index asc).
        const int ii = r & 3;
        #pragma unroll
        for (int e = 0; e < 4; ++e) {
          const float v  = acc[mi][ni][e];
          const float v1 = __shfl_xor(v, 1);
          const float v2 = __shfl_xor(v, 2);
          const float v3 = __shfl_xor(v, 3);
          int cnt = 0;
          { const int j = ii ^ 1; cnt += (v1 > v) || (v1 == v && j < ii); }
          { const int j = ii ^ 2; cnt += (v2 > v) || (v2 == v && j < ii); }
          { const int j = ii ^ 3; cnt += (v3 > v) || (v3 == v && j < ii); }
          Cb[(size_t)(row0 + e) * N + col] =
              (cnt < 2) ? (unsigned short)0x3F80 : (unsigned short)0;
        }
      }
    }
  }
}

// ---------------------------------------------------------------------------
// Flash attention: 512 blocks; XCD-chunked swizzle keeps 4 consecutive bh
// (4 MB K/V = one XCD's L2) per XCD. Block processes q-tiles {pair, 31-pair}
// sequentially -> uniform 33 KV-iterations. 4 waves x 16 q-rows, KBLK=64.
// K/V loads for kvt+1 issued right after the write-barrier (latency hiding).
// setprio(1) around MFMA clusters (T5, attn-positive).
// Q [bh][s][128], K [bh][s][128], Vt [bh][128][s]; Out token-major [4096][2048].
// ---------------------------------------------------------------------------
__global__ __launch_bounds__(256)
void attn_fa(const unsigned short* __restrict__ Qh, const unsigned short* __restrict__ Kh,
             const unsigned short* __restrict__ Vt, unsigned short* __restrict__ Out)
{
  __shared__ alignas(16) unsigned short Ks[64 * 128];
  __shared__ alignas(16) unsigned short Vs[128 * 64];
  __shared__ alignas(16) unsigned short Ps[4][1024];
  const int tid = threadIdx.x, lane = tid & 63, wid = tid >> 6;
  const int r = lane & 15, g = lane >> 4;
  const int sw = xcd_swizzle(blockIdx.y * gridDim.x + blockIdx.x, gridDim.x * gridDim.y);
  const int pair = sw % 16, bh = sw / 16;
  const int b = bh >> 4, h = bh & 15;
  const f32x4 zero = {0.f, 0.f, 0.f, 0.f};

  i32x4 kr[4], vr[4];
  auto issue_kv = [&](int kvt) {
    #pragma unroll
    for (int i = 0; i < 4; ++i) {
      const int c = i * 256 + tid;
      {
        const int row = c >> 4, slot = c & 15;
        kr[i] = *(const i32x4*)(Kh + ((size_t)bh * 2048 + kvt * 64 + row) * 128 + slot * 8);
      }
      {
        const int row = c >> 3, slot = c & 7;
        vr[i] = *(const i32x4*)(Vt + ((size_t)bh * 128 + row) * 2048 + kvt * 64 + slot * 8);
      }
    }
  };

  for (int half = 0; half < 2; ++half) {
    const int qt = half ? (31 - pair) : pair;
    const int qrow0 = qt * 64 + wid * 16;

    bf16x8 qf[4];
    {
      const unsigned short* qp = Qh + ((size_t)bh * 2048 + qrow0 + r) * 128;
      #pragma unroll
      for (int ks = 0; ks < 4; ++ks) qf[ks] = ld_frag(qp + ks * 32 + g * 8);
    }
    f32x4 oacc[8];
    #pragma unroll
    for (int i = 0; i < 8; ++i) oacc[i] = zero;
    float m_run[4] = {-1e30f, -1e30f, -1e30f, -1e30f};
    float l_run[4] = {0.f, 0.f, 0.f, 0.f};

    issue_kv(0);
    for (int kvt = 0; kvt <= qt; ++kvt) {
      __syncthreads();   // Ks/Vs free (prev compute done)
      #pragma unroll
      for (int i = 0; i < 4; ++i) {
        const int c = i * 256 + tid;
        {
          const int row = c >> 4, slot = c & 15;
          *(i32x4*)&Ks[row * 128 + ((slot ^ (row & 7)) << 3)] = kr[i];
        }
        {
          const int row = c >> 3, slot = c & 7;
          *(i32x4*)&Vs[row * 64 + ((slot ^ (row & 7)) << 3)] = vr[i];
        }
      }
      __syncthreads();
      if (kvt < qt) issue_kv(kvt + 1);   // loads fly under compute

      f32x4 sc[4];
      #pragma unroll
      for (int ni = 0; ni < 4; ++ni) sc[ni] = zero;
      __builtin_amdgcn_s_setprio(1);
      #pragma unroll
      for (int ks = 0; ks < 4; ++ks) {
        const int slot = (ks << 2) | g;
        #pragma unroll
        for (int ni = 0; ni < 4; ++ni) {
          const int krow = ni * 16 + r;
          bf16x8 kf = ld_frag(&Ks[krow * 128 + ((slot ^ (krow & 7)) << 3)]);
          sc[ni] = mfma16(qf[ks], kf, sc[ni]);
        }
      }
      __builtin_amdgcn_s_setprio(0);
      const float sscale = 0.08838834764831845f;   // 1/sqrt(128)
      if (kvt == qt) {
        #pragma unroll
        for (int ni = 0; ni < 4; ++ni) {
          const int kvg = kvt * 64 + ni * 16 + r;
          #pragma unroll
          for (int e = 0; e < 4; ++e) {
            const int qg = qrow0 + g * 4 + e;
            const float s = sc[ni][e] * sscale;
            sc[ni][e] = (kvg > qg) ? -1e30f : s;
          }
        }
      } else {
        #pragma unroll
        for (int ni = 0; ni < 4; ++ni) {
          #pragma unroll
          for (int e = 0; e < 4; ++e) sc[ni][e] *= sscale;
        }
      }
      float corr[4];
      #pragma unroll
      for (int e = 0; e < 4; ++e) {
        float mx = fmaxf(fmaxf(sc[0][e], sc[1][e]), fmaxf(sc[2][e], sc[3][e]));
        mx = fmaxf(mx, __shfl_xor(mx, 1));
        mx = fmaxf(mx, __shfl_xor(mx, 2));
        mx = fmaxf(mx, __shfl_xor(mx, 4));
        mx = fmaxf(mx, __shfl_xor(mx, 8));
        const float mn = fmaxf(m_run[e], mx);
        corr[e] = exp2f((m_run[e] - mn) * 1.4426950408889634f);
        m_run[e] = mn;
      }
      float psum[4] = {0.f, 0.f, 0.f, 0.f};
      #pragma unroll
      for (int ni = 0; ni < 4; ++ni) {
        #pragma unroll
        for (int e = 0; e < 4; ++e) {
          const float p = exp2f((sc[ni][e] - m_run[e]) * 1.4426950408889634f);
          sc[ni][e] = p;
          psum[e] += p;
        }
      }
      #pragma unroll
      for (int e = 0; e < 4; ++e) {
        float s = psum[e];
        s += __shfl_xor(s, 1);
        s += __shfl_xor(s, 2);
        s += __shfl_xor(s, 4);
        s += __shfl_xor(s, 8);
        l_run[e] = l_run[e] * corr[e] + s;
      }
      #pragma unroll
      for (int nf = 0; nf < 8; ++nf) {
        #pragma unroll
        for (int e = 0; e < 4; ++e) oacc[nf][e] *= corr[e];
      }
      #pragma unroll
      for (int ni = 0; ni < 4; ++ni) {
        #pragma unroll
        for (int e = 0; e < 4; ++e) {
          const int prow = g * 4 + e;
          const int col = ni * 16 + r;
          const int slot = col >> 3;
          Ps[wid][prow * 64 + ((slot ^ (prow & 7)) << 3) + (col & 7)] = f2bf_u(sc[ni][e]);
        }
      }
      __builtin_amdgcn_s_setprio(1);
      #pragma unroll
      for (int ks = 0; ks < 2; ++ks) {
        const int slot = (ks << 2) | g;
        bf16x8 pf = ld_frag(&Ps[wid][r * 64 + ((slot ^ (r & 7)) << 3)]);
        #pragma unroll
        for (int nf = 0; nf < 8; ++nf) {
          const int vrow = nf * 16 + r;
          bf16x8 vf = ld_frag(&Vs[vrow * 64 + ((slot ^ (vrow & 7)) << 3)]);
          oacc[nf] = mfma16(pf, vf, oacc[nf]);
        }
      }
      __builtin_amdgcn_s_setprio(0);
    }
    #pragma unroll
    for (int e = 0; e < 4; ++e) {
      const float inv = 1.f / l_run[e];
      const int qg = qrow0 + g * 4 + e;
      #pragma unroll
      for (int nf = 0; nf < 8; ++nf) {
        const int d = nf * 16 + r;
        Out[((size_t)(b * 2048 + qg)) * 2048 + h * 128 + d] = f2bf_u(oacc[nf][e] * inv);
      }
    }
  }
}

// ---------------------------------------------------------------------------
extern "C" void kernel_launch(void* const* d_in, const int* in_sizes, int n_in,
                              void* d_out, int out_size, void* d_ws, size_t ws_size,
                              hipStream_t stream)
{
  (void)in_sizes; (void)n_in; (void)out_size; (void)ws_size;
  const float* hid   = (const float*)d_in[0];
  const float* Wq    = (const float*)d_in[1];
  const float* bq    = (const float*)d_in[2];
  const float* Wk    = (const float*)d_in[3];
  const float* bk    = (const float*)d_in[4];
  const float* Wv    = (const float*)d_in[5];
  const float* bv    = (const float*)d_in[6];
  const float* Wo    = (const float*)d_in[7];
  const float* sq    = (const float*)d_in[8];
  const float* sk    = (const float*)d_in[9];
  const float* sv    = (const float*)d_in[10];
  const float* so    = (const float*)d_in[11];
  const float* permq = (const float*)d_in[12];
  const float* permo = (const float*)d_in[13];
  const int* pos     = (const int*)d_in[14];      // int32 per harness convention
  float* out = (float*)d_out;
  char* ws = (char*)d_ws;

  // ---- workspace layout (total ~178 MB) ----
  constexpr size_t OFF_ROWS = 0;                                   // 32KB
  constexpr size_t OFF_COLS = OFF_ROWS + (size_t)4 * 2048 * 4;     // 32KB
  constexpr size_t OFF_PART = OFF_COLS + (size_t)4 * 2048 * 4;     // 1MB
  constexpr size_t OFF_COS  = OFF_PART + (size_t)4 * 32 * 2048 * 4;
  constexpr size_t OFF_SIN  = OFF_COS + (size_t)2048 * 64 * 4;
  constexpr size_t SZ_PERM  = (size_t)2048 * 2048 * 2;             // 8MB
  constexpr size_t OFF_A    = OFF_SIN + (size_t)2048 * 64 * 4;     // 48MB region
  constexpr size_t OFF_PTQH = OFF_A;
  constexpr size_t OFF_PTQL = OFF_PTQH + SZ_PERM;
  constexpr size_t OFF_PTOH = OFF_PTQL + SZ_PERM;
  constexpr size_t OFF_PTOL = OFF_PTOH + SZ_PERM;
  constexpr size_t OFF_PBQ  = OFF_PTOL + SZ_PERM;
  constexpr size_t OFF_PBO  = OFF_PBQ + SZ_PERM;
  constexpr size_t SZ_M8    = (size_t)8192 * 2048 * 2;             // 32MB
  constexpr size_t OFF_B    = OFF_PBO + SZ_PERM;   // mhi   (later: yqkv spans B..C)
  constexpr size_t OFF_C    = OFF_B + SZ_M8;       // mlo
  constexpr size_t OFF_D    = OFF_C + SZ_M8;       // hard  (later: xbf @+0, att @+16MB)
  constexpr size_t OFF_E    = OFF_D + SZ_M8;       // wfin
  // END = OFF_E + SZ_M8 = 186,712,064 bytes

  float* rowsums = (float*)(ws + OFF_ROWS);
  float* colsums = (float*)(ws + OFF_COLS);
  float* part    = (float*)(ws + OFF_PART);
  float* cost    = (float*)(ws + OFF_COS);
  float* sint    = (float*)(ws + OFF_SIN);
  unsigned short* ptqh = (unsigned short*)(ws + OFF_PTQH);
  unsigned short* ptql = (unsigned short*)(ws + OFF_PTQL);
  unsigned short* ptoh = (unsigned short*)(ws + OFF_PTOH);
  unsigned short* ptol = (unsigned short*)(ws + OFF_PTOL);
  unsigned short* pbq  = (unsigned short*)(ws + OFF_PBQ);
  unsigned short* pbo  = (unsigned short*)(ws + OFF_PBO);
  unsigned short* mhi  = (unsigned short*)(ws + OFF_B);
  unsigned short* mlo  = (unsigned short*)(ws + OFF_C);
  unsigned short* hard = (unsigned short*)(ws + OFF_D);
  unsigned short* wfin = (unsigned short*)(ws + OFF_E);
  // aliases (lifetimes verified stage-by-stage):
  unsigned short* yqkv = (unsigned short*)(ws + OFF_B);            // 48MB of B..C
  unsigned short* qhb  = (unsigned short*)(ws + OFF_A);            // 16MB
  unsigned short* khb  = (unsigned short*)(ws + OFF_A + 2 * SZ_PERM);
  unsigned short* vtg  = (unsigned short*)(ws + OFF_A + 4 * SZ_PERM);
  unsigned short* xbf  = (unsigned short*)(ws + OFF_D);            // 16MB
  unsigned short* att  = (unsigned short*)(ws + OFF_D + SZ_M8 / 2);

  Ptr4 Wptrs{{Wq, Wk, Wv, Wo}};
  Ptr4 Sptrs{{sq, sk, sv, so}};
  Ptr4 BiasP{{bq, bk, bv, nullptr}};
  Ptr4 NoAux{{nullptr, nullptr, nullptr, nullptr}};
  constexpr int NOSW = 1 << 30;

  // 1) |W| sums
  k_rowsum<<<dim3(2048, 4), 256, 0, stream>>>(Wptrs, rowsums);
  k_colsum_part<<<dim3(8, 32, 4), 256, 0, stream>>>(Wptrs, part);
  k_colsum_red<<<32, 256, 0, stream>>>(part, colsums);
  // 2) metric (hi/lo split) for all 4 mats, stacked [8192][2048]
  k_metric<<<16384, 256, 0, stream>>>(Wptrs, Sptrs, rowsums, colsums, mhi, mlo);
  // 3) perm prep: transposed hi/lo split + fused plain bf16 cast
  k_perm_prep<<<dim3(32, 32, 2), 256, 0, stream>>>(permq, permo, ptqh, ptql, ptoh, ptol, pbq, pbo);
  // 4) hard = top2of4(metric @ perm)  — merged qkv+o launch, B switch at row 6144
  gemm_bt<3, 1><<<dim3(16, 64), 256, 0, stream>>>(mhi, mlo, ptqh, ptql, ptoh, ptol, 6144,
                                                  nullptr, hard, NoAux, 8192, 2048, 2048);
  // 5) Wfinal = W * (hard @ perm^T) — merged, aux p[row>>11] selects Wq..Wo
  gemm_bt<1, 0><<<dim3(16, 64), 256, 0, stream>>>(hard, nullptr, pbq, nullptr, pbo, nullptr, 6144,
                                                  nullptr, wfin, Wptrs, 8192, 2048, 2048);
  // 6) x -> bf16 ; y_qkv = x @ Wfinal^T + bias (bf16, stacked N=6144)
  k_cast_bf<<<4096, 256, 0, stream>>>(hid, xbf);
  gemm_bt<2, 0><<<dim3(48, 32), 256, 0, stream>>>(xbf, nullptr, wfin, nullptr, wfin, nullptr, NOSW,
                                                  nullptr, yqkv, BiasP, 4096, 6144, 2048);
  // 7) RoPE tables, q/k reshape+rope (vectorized), v transpose
  k_rope_tab<<<512, 256, 0, stream>>>(cost, sint);
  k_rope_reshape<<<4096, 256, 0, stream>>>(yqkv, pos, cost, sint, qhb, khb);
  k_vtrans<<<dim3(32, 32), 256, 0, stream>>>(yqkv, vtg);
  // 8) flash attention (paired q-tiles, pipelined K/V loads, XCD swizzle)
  attn_fa<<<dim3(16, 32), 256, 0, stream>>>(qhb, khb, vtg, att);
  // 9) out = attn @ Wo_final^T (f32)
  gemm_bt<0, 0><<<dim3(16, 32), 256, 0, stream>>>(att, nullptr, wfin + (size_t)6144 * 2048, nullptr,
                                                  wfin + (size_t)6144 * 2048, nullptr, NOSW,
                                                  out, nullptr, NoAux, 4096, 2048, 2048);
}

// Round 9
// 648.590 us; speedup vs baseline: 1.0163x; 1.0163x over previous
//
#include <hip/hip_runtime.h>
#include <cstdint>
#include <cstddef>

typedef __attribute__((ext_vector_type(4))) float  f32x4;
typedef __attribute__((ext_vector_type(4))) int    i32x4;
typedef __attribute__((ext_vector_type(8))) short  s16x8;
typedef __attribute__((ext_vector_type(4))) short  s16x4;
typedef __attribute__((ext_vector_type(8))) __bf16 bf16x8;

struct Ptr4 { const float* p[4]; };

#define DEV __device__ __forceinline__

DEV unsigned short f2bf_u(float x) {
  unsigned u = __builtin_bit_cast(unsigned, x);
  u += 0x7fffu + ((u >> 16) & 1u);
  return (unsigned short)(u >> 16);
}
DEV float bfu2f(unsigned short u) {
  return __builtin_bit_cast(float, ((unsigned)u) << 16);
}
DEV bf16x8 ld_frag(const unsigned short* p) {
  s16x8 v = *(const s16x8*)p;
  return __builtin_bit_cast(bf16x8, v);
}
DEV f32x4 mfma16(bf16x8 a, bf16x8 b, f32x4 c) {
  return __builtin_amdgcn_mfma_f32_16x16x32_bf16(a, b, c, 0, 0, 0);
}
// async global->LDS, 16B per lane; LDS dest = wave-uniform base + lane*16
DEV void gload_lds16(const unsigned short* g, unsigned short* l) {
  __builtin_amdgcn_global_load_lds(
      (const __attribute__((address_space(1))) unsigned int*)g,
      (__attribute__((address_space(3))) unsigned int*)l, 16, 0, 0);
}
// XCD-chunked bijective block-id swizzle (requires nwg % 8 == 0).
// Measured (r5/r7/r8 A/B): helps attention (+) and the non-split GEMMs
// (B-panel reuse across row-tiles, ~8us combined); HURTS the split GEMM
// (192.5 -> 207.8 us). Applied selectively via template flag.
DEV int xcd_swizzle(int bid, int nwg) {
  const int q8 = nwg >> 3;
  return (bid & 7) * q8 + (bid >> 3);
}

// ---------------------------------------------------------------------------
// |W| row sums (one block per row, deterministic)
// ---------------------------------------------------------------------------
__global__ __launch_bounds__(256)
void k_rowsum(Ptr4 Ws, float* __restrict__ rowsums)
{
  const int row = blockIdx.x, mat = blockIdx.y, tid = threadIdx.x;
  const float* W = Ws.p[mat] + (size_t)row * 2048;
  float s = 0.f;
  #pragma unroll
  for (int p = 0; p < 2; ++p) {
    f32x4 v = *(const f32x4*)(W + p * 1024 + tid * 4);
    s += fabsf(v[0]) + fabsf(v[1]) + fabsf(v[2]) + fabsf(v[3]);
  }
  #pragma unroll
  for (int off = 1; off < 64; off <<= 1) s += __shfl_xor(s, off);
  __shared__ float red[4];
  if ((tid & 63) == 0) red[tid >> 6] = s;
  __syncthreads();
  if (tid == 0) rowsums[mat * 2048 + row] = red[0] + red[1] + red[2] + red[3];
}

// |W| column sums: partial over 64-row stripes, then reduce (no atomics)
__global__ __launch_bounds__(256)
void k_colsum_part(Ptr4 Ws, float* __restrict__ part)
{
  const int c = blockIdx.x * 256 + threadIdx.x;
  const int r0 = blockIdx.y * 64;
  const int mat = blockIdx.z;
  const float* W = Ws.p[mat];
  float s = 0.f;
  for (int rr = 0; rr < 64; ++rr) s += fabsf(W[(size_t)(r0 + rr) * 2048 + c]);
  part[((size_t)mat * 32 + blockIdx.y) * 2048 + c] = s;
}
__global__ __launch_bounds__(256)
void k_colsum_red(const float* __restrict__ part, float* __restrict__ colsums)
{
  const int gid = blockIdx.x * 256 + threadIdx.x;   // 4*2048
  const int mat = gid >> 11, c = gid & 2047;
  float s = 0.f;
  #pragma unroll
  for (int j = 0; j < 32; ++j) s += part[((size_t)mat * 32 + j) * 2048 + c];
  colsums[gid] = s;
}

// metric[r,c] = |W|*(1/colsum[c] + 1/rowsum[r]) * sqrt(scaler[c]) ; hi/lo bf16 split
__global__ __launch_bounds__(256)
void k_metric(Ptr4 Ws, Ptr4 Ss, const float* __restrict__ rowsums,
              const float* __restrict__ colsums,
              unsigned short* __restrict__ mhi, unsigned short* __restrict__ mlo)
{
  const size_t idx4 = ((size_t)blockIdx.x * 256 + threadIdx.x) * 4;
  const int row = (int)(idx4 >> 11);
  const int c = (int)(idx4 & 2047);
  const int mat = row >> 11, rl = row & 2047;
  const float rs = rowsums[mat * 2048 + rl];
  f32x4 w  = *(const f32x4*)(Ws.p[mat] + (size_t)rl * 2048 + c);
  f32x4 cs = *(const f32x4*)(colsums + mat * 2048 + c);
  f32x4 sv = *(const f32x4*)(Ss.p[mat] + c);
  s16x4 hv, lv;
  #pragma unroll
  for (int j = 0; j < 4; ++j) {
    const float a = fabsf(w[j]);
    const float m = (a / cs[j] + a / rs) * sqrtf(sv[j]);
    const unsigned short hb = f2bf_u(m);
    hv[j] = (short)hb;
    lv[j] = (short)f2bf_u(m - bfu2f(hb));
  }
  *(s16x4*)(mhi + idx4) = hv;
  *(s16x4*)(mlo + idx4) = lv;
}

// perm -> permT hi/lo bf16 (tiled transpose) + fused plain bf16 cast
__global__ __launch_bounds__(256)
void k_perm_prep(const float* __restrict__ pq, const float* __restrict__ po,
                 unsigned short* __restrict__ thi_q, unsigned short* __restrict__ tlo_q,
                 unsigned short* __restrict__ thi_o, unsigned short* __restrict__ tlo_o,
                 unsigned short* __restrict__ pb_q, unsigned short* __restrict__ pb_o)
{
  __shared__ float T[64 * 65];
  const int which = blockIdx.z;
  const float* src = which ? po : pq;
  unsigned short* thi = which ? thi_o : thi_q;
  unsigned short* tlo = which ? tlo_o : tlo_q;
  unsigned short* pb  = which ? pb_o : pb_q;
  const int rb = blockIdx.y * 64, cb = blockIdx.x * 64, tid = threadIdx.x;
  #pragma unroll
  for (int i = 0; i < 4; ++i) {
    const int cc = i * 256 + tid;
    const int rowl = cc >> 4, c4 = (cc & 15) * 4;
    f32x4 v = *(const f32x4*)(src + (size_t)(rb + rowl) * 2048 + cb + c4);
    s16x4 pc;
    #pragma unroll
    for (int j = 0; j < 4; ++j) {
      T[rowl * 65 + c4 + j] = v[j];
      pc[j] = (short)f2bf_u(v[j]);
    }
    *(s16x4*)(pb + (size_t)(rb + rowl) * 2048 + cb + c4) = pc;
  }
  __syncthreads();
  #pragma unroll
  for (int i = 0; i < 4; ++i) {
    const int cc = i * 256 + tid;
    const int rowt = cc >> 4, c4 = (cc & 15) * 4;
    s16x4 hh, ll;
    #pragma unroll
    for (int j = 0; j < 4; ++j) {
      const float v = T[(c4 + j) * 65 + rowt];
      const unsigned short hb = f2bf_u(v);
      hh[j] = (short)hb;
      ll[j] = (short)f2bf_u(v - bfu2f(hb));
    }
    const size_t off = (size_t)(cb + rowt) * 2048 + rb + c4;
    *(s16x4*)(thi + off) = hh;
    *(s16x4*)(tlo + off) = ll;
  }
}

// plain f32 -> bf16 cast (8 elems/thread)
__global__ __launch_bounds__(256)
void k_cast_bf(const float* __restrict__ src, unsigned short* __restrict__ dst)
{
  const size_t i = ((size_t)blockIdx.x * 256 + threadIdx.x) * 8;
  f32x4 a = *(const f32x4*)(src + i);
  f32x4 b = *(const f32x4*)(src + i + 4);
  s16x8 o;
  #pragma unroll
  for (int j = 0; j < 4; ++j) o[j] = (short)f2bf_u(a[j]);
  #pragma unroll
  for (int j = 0; j < 4; ++j) o[4 + j] = (short)f2bf_u(b[j]);
  *(s16x8*)(dst + i) = o;
}

// RoPE tables [2048][64]
__global__ __launch_bounds__(256)
void k_rope_tab(float* __restrict__ ct, float* __restrict__ st)
{
  const int gid = blockIdx.x * 256 + threadIdx.x;
  const int s = gid >> 6, i = gid & 63;
  const float ex = (float)(2 * i) / 128.f;
  const float inv = 1.f / powf(10000.f, ex);
  const float f = (float)s * inv;
  ct[gid] = cosf(f);
  st[gid] = sinf(f);
}

// y_qkv [4096][6144] -> q,k head-major [2][16][2048][128] with RoPE.
// Vectorized: one thread = 8 consecutive d (s16x8 loads; partner chunk d8^8).
__global__ __launch_bounds__(256)
void k_rope_reshape(const unsigned short* __restrict__ yqkv, const int* __restrict__ pos,
                    const float* __restrict__ ct, const float* __restrict__ st,
                    unsigned short* __restrict__ qo, unsigned short* __restrict__ ko)
{
  const int gid = blockIdx.x * 256 + threadIdx.x;   // 2*16*2048*16 chunks
  const int d8 = gid & 15;
  const int s = (gid >> 4) & 2047;
  const int h = (gid >> 15) & 15;
  const int b = gid >> 19;
  const int t = b * 2048 + s;
  const int p = pos[t];
  const size_t yb = (size_t)t * 6144 + h * 128;
  s16x8 qv = *(const s16x8*)(yqkv + yb + d8 * 8);
  s16x8 qp = *(const s16x8*)(yqkv + yb + (d8 ^ 8) * 8);
  s16x8 kv = *(const s16x8*)(yqkv + yb + 2048 + d8 * 8);
  s16x8 kp = *(const s16x8*)(yqkv + yb + 2048 + (d8 ^ 8) * 8);
  const int dh0 = (d8 & 7) * 8;
  const float sgn = (d8 < 8) ? -1.f : 1.f;
  s16x8 qo8, ko8;
  #pragma unroll
  for (int j = 0; j < 8; ++j) {
    const float cv = ct[p * 64 + dh0 + j];
    const float sv = st[p * 64 + dh0 + j];
    const float q0 = bfu2f((unsigned short)qv[j]);
    const float k0 = bfu2f((unsigned short)kv[j]);
    const float q1 = sgn * bfu2f((unsigned short)qp[j]);
    const float k1 = sgn * bfu2f((unsigned short)kp[j]);
    qo8[j] = (short)f2bf_u(q0 * cv + q1 * sv);
    ko8[j] = (short)f2bf_u(k0 * cv + k1 * sv);
  }
  const size_t o = ((size_t)(b * 16 + h) * 2048 + s) * 128 + d8 * 8;
  *(s16x8*)(qo + o) = qo8;
  *(s16x8*)(ko + o) = ko8;
}

// y_qkv v-part -> Vt global [2][16][128][2048] (LDS-tiled transpose)
__global__ __launch_bounds__(256)
void k_vtrans(const unsigned short* __restrict__ yqkv, unsigned short* __restrict__ vt)
{
  __shared__ float T[64 * 129];
  const int st = blockIdx.x, bh = blockIdx.y, tid = threadIdx.x;
  const int b = bh >> 4, h = bh & 15;
  #pragma unroll
  for (int i = 0; i < 4; ++i) {
    const int c = i * 256 + tid;           // 0..1023
    const int sl = c >> 4, d8 = (c & 15) * 8;
    s16x8 v = *(const s16x8*)(yqkv + (size_t)(b * 2048 + st * 64 + sl) * 6144 + 4096 + h * 128 + d8);
    #pragma unroll
    for (int j = 0; j < 8; ++j) T[sl * 129 + d8 + j] = bfu2f((unsigned short)v[j]);
  }
  __syncthreads();
  #pragma unroll
  for (int i = 0; i < 4; ++i) {
    const int c = i * 256 + tid;
    const int d = c >> 3, s8 = (c & 7) * 8;
    s16x8 o;
    #pragma unroll
    for (int j = 0; j < 8; ++j) o[j] = (short)f2bf_u(T[(s8 + j) * 129 + d]);
    *(s16x8*)(vt + ((size_t)bh * 128 + d) * 2048 + st * 64 + s8) = o;
  }
}

// ---------------------------------------------------------------------------
// Generic bf16 MFMA GEMM, C[M,N] = A[M,K] @ B[N,K]^T, 128x128 tile, BK=32.
// SWZ: XCD-chunked block swizzle (ON for non-split GEMMs with B-panel reuse;
//      OFF for the split GEMM — measured -8% there, r5-vs-r7 A/B).
// SPLIT=1: single-buffer hi+lo (32KB), 2 barriers, prefetch under the 48-MFMA
//          block — the measured-best structure (r5: 192.5us, MfmaUtil 50%).
//          (dbuf 64KB tried r8: occupancy 26.7->21.7%, net 0 — reverted.)
// SPLIT=0: double-buffered LDS (32KB), ONE barrier per K-step.
// Staging via global_load_lds (16B/lane, linear LDS dest); global source is
// pre-swizzled (chunk ^= (row>>1)&3, conflict-free 2-way) and ds_read applies
// the same XOR (rule #21: both sides, same involution).
// MODE 0: Cf = acc (f32).
// MODE 1: Cb = bf16(acc * aux.p[row>>11][row&2047, col]).
// MODE 2: Cb = bf16(acc + aux.p[col>>11][col&2047]).
// MODE 3: fused top-2-of-4 over col blocks -> Cb in {bf16 1.0, 0.0}.
// SPLIT: A,B given as hi/lo bf16 pairs; acc = Al*Bh + Ah*Bl + Ah*Bh.
// ---------------------------------------------------------------------------
template<int MODE, int SPLIT, int SWZ>
__global__ __launch_bounds__(256)
void gemm_bt(const unsigned short* __restrict__ Ahi, const unsigned short* __restrict__ Alo,
             const unsigned short* __restrict__ Bhi_1, const unsigned short* __restrict__ Blo_1,
             const unsigned short* __restrict__ Bhi_2, const unsigned short* __restrict__ Blo_2,
             int bswitch,
             float* __restrict__ Cf, unsigned short* __restrict__ Cb,
             Ptr4 aux, int M, int N, int K)
{
  __shared__ alignas(16) unsigned short As[2 * 4096];
  __shared__ alignas(16) unsigned short Bs[2 * 4096];
  const int tid = threadIdx.x;
  const int lane = tid & 63, wid = tid >> 6;
  const int wm = wid >> 1, wn = wid & 1;
  const int r = lane & 15, g = lane >> 4;
  int bx = blockIdx.x, by = blockIdx.y;
  if (SWZ) {
    const int nwg = gridDim.x * gridDim.y;
    const int sw = xcd_swizzle(blockIdx.y * gridDim.x + blockIdx.x, nwg);
    bx = sw % gridDim.x; by = sw / gridDim.x;
  }
  const int mbase = by * 128;
  const int nbase = bx * 128;
  const int KT = K >> 5;
  (void)M;
  const unsigned short* Bhi = (mbase >= bswitch) ? Bhi_2 : Bhi_1;
  const unsigned short* Blo = (mbase >= bswitch) ? Blo_2 : Blo_1;

  const f32x4 zero = {0.f, 0.f, 0.f, 0.f};
  f32x4 acc[4][4];
  #pragma unroll
  for (int i = 0; i < 4; ++i) {
    #pragma unroll
    for (int j = 0; j < 4; ++j) acc[i][j] = zero;
  }

  // staging geometry: wave wid covers rows [wid*32, wid*32+32), 2 issues of
  // 16 rows (1KB each). Lane: row_local = lane>>2, chunk = lane&3 (16B).
  const int srl = lane >> 2;
  const int sch = lane & 3;

  // SPLIT: hi plane at [0,4096), lo plane at [4096,8192) (single buffer).
  // non-SPLIT: buf0 at [0,4096), buf1 at [4096,8192) (double buffer).
  auto issue_tile = [&](int kt, int buf) {
    const size_t kb = (size_t)kt * 32;
    #pragma unroll
    for (int i = 0; i < 2; ++i) {
      const int rbase = wid * 32 + i * 16;
      const int rloc = rbase + srl;
      const int sc = ((sch ^ ((rloc >> 1) & 3)) << 3);   // pre-swizzled source
      const size_t ga = (size_t)(mbase + rloc) * K + kb + sc;
      const size_t gb = (size_t)(nbase + rloc) * K + kb + sc;
      gload_lds16(Ahi + ga, &As[buf * 4096 + rbase * 32]);  // wave-uniform base
      gload_lds16(Bhi + gb, &Bs[buf * 4096 + rbase * 32]);
      if (SPLIT) {
        gload_lds16(Alo + ga, &As[4096 + rbase * 32]);
        gload_lds16(Blo + gb, &Bs[4096 + rbase * 32]);
      }
    }
  };

  if (SPLIT) {
    issue_tile(0, 0);
    for (int kt = 0; kt < KT; ++kt) {
      __syncthreads();   // loads complete (compiler drains vmcnt before barrier)

      bf16x8 ah[4], bfr[4], al[4], bl[4];
      #pragma unroll
      for (int mi = 0; mi < 4; ++mi) {
        const int arow = wm * 64 + mi * 16 + r;
        const int sw2 = ((g ^ ((arow >> 1) & 3)) << 3);
        ah[mi] = ld_frag(&As[arow * 32 + sw2]);
        al[mi] = ld_frag(&As[4096 + arow * 32 + sw2]);
      }
      #pragma unroll
      for (int ni = 0; ni < 4; ++ni) {
        const int brow = wn * 64 + ni * 16 + r;
        const int sw2 = ((g ^ ((brow >> 1) & 3)) << 3);
        bfr[ni] = ld_frag(&Bs[brow * 32 + sw2]);
        bl[ni] = ld_frag(&Bs[4096 + brow * 32 + sw2]);
      }
      __syncthreads();   // all waves' frag reads landed in registers
      if (kt + 1 < KT) issue_tile(kt + 1, 0);  // loads fly under the MFMAs

      #pragma unroll
      for (int mi = 0; mi < 4; ++mi) {
        #pragma unroll
        for (int ni = 0; ni < 4; ++ni) {
          acc[mi][ni] = mfma16(al[mi], bfr[ni], acc[mi][ni]);
          acc[mi][ni] = mfma16(ah[mi], bl[ni], acc[mi][ni]);
          acc[mi][ni] = mfma16(ah[mi], bfr[ni], acc[mi][ni]);
        }
      }
    }
  } else {
    issue_tile(0, 0);
    int cur = 0;
    for (int kt = 0; kt < KT; ++kt) {
      __syncthreads();   // buf[cur] staged; prior readers of buf[cur^1] done
      if (kt + 1 < KT) issue_tile(kt + 1, cur ^ 1);  // overlap ds_read + MFMA

      bf16x8 ah[4], bfr[4];
      #pragma unroll
      for (int mi = 0; mi < 4; ++mi) {
        const int arow = wm * 64 + mi * 16 + r;
        ah[mi] = ld_frag(&As[cur * 4096 + arow * 32 + ((g ^ ((arow >> 1) & 3)) << 3)]);
      }
      #pragma unroll
      for (int ni = 0; ni < 4; ++ni) {
        const int brow = wn * 64 + ni * 16 + r;
        bfr[ni] = ld_frag(&Bs[cur * 4096 + brow * 32 + ((g ^ ((brow >> 1) & 3)) << 3)]);
      }
      #pragma unroll
      for (int mi = 0; mi < 4; ++mi) {
        #pragma unroll
        for (int ni = 0; ni < 4; ++ni)
          acc[mi][ni] = mfma16(ah[mi], bfr[ni], acc[mi][ni]);
      }
      cur ^= 1;
    }
  }

  #pragma unroll
  for (int mi = 0; mi < 4; ++mi) {
    #pragma unroll
    for (int ni = 0; ni < 4; ++ni) {
      const int row0 = mbase + wm * 64 + mi * 16 + g * 4;
      const int col  = nbase + wn * 64 + ni * 16 + r;
      if (MODE == 0) {
        #pragma unroll
        for (int e = 0; e < 4; ++e)
          Cf[(size_t)(row0 + e) * N + col] = acc[mi][ni][e];
      } else if (MODE == 1) {
        const float* wsrc = aux.p[row0 >> 11];
        #pragma unroll
        for (int e = 0; e < 4; ++e) {
          const float mval = wsrc[(size_t)((row0 + e) & 2047) * 2048 + col];
          Cb[(size_t)(row0 + e) * N + col] = f2bf_u(acc[mi][ni][e] * mval);
        }
      } else if (MODE == 2) {
        const float* bp = aux.p[col >> 11];
        const float bb = bp[col & 2047];
        #pragma unroll
        for (int e = 0; e < 4; ++e)
          Cb[(size_t)(row0 + e) * N + col] = f2bf_u(acc[mi][ni][e] + bb);
      } else {
        // MODE 3: top-2-of-4 across the 4-col block; partners live in lanes
        // r^1, r^2, r^3 (same g). Rank by (value desc, index asc).
        const int ii = r & 3;
        #pragma unroll
        for (int e = 0; e < 4; ++e) {
          const float v  = acc[mi][ni][e];
          const float v1 = __shfl_xor(v, 1);
          const float v2 = __shfl_xor(v, 2);
          const float v3 = __shfl_xor(v, 3);
          int cnt = 0;
          { const int j = ii ^ 1; cnt += (v1 > v) || (v1 == v && j < ii); }
          { const int j = ii ^ 2; cnt += (v2 > v) || (v2 == v && j < ii); }
          { const int j = ii ^ 3; cnt += (v3 > v) || (v3 == v && j < ii); }
          Cb[(size_t)(row0 + e) * N + col] =
              (cnt < 2) ? (unsigned short)0x3F80 : (unsigned short)0;
        }
      }
    }
  }
}

// ---------------------------------------------------------------------------
// Flash attention: 512 blocks; XCD-chunked swizzle keeps 4 consecutive bh
// (4 MB K/V = one XCD's L2) per XCD. Block processes q-tiles {pair, 31-pair}
// sequentially -> uniform 33 KV-iterations. 4 waves x 16 q-rows, KBLK=64.
// K/V loads for kvt+1 issued right after the write-barrier (latency hiding).
// setprio(1) around MFMA clusters (T5, attn-positive).
// Q [bh][s][128], K [bh][s][128], Vt [bh][128][s]; Out token-major [4096][2048].
// ---------------------------------------------------------------------------
__global__ __launch_bounds__(256)
void attn_fa(const unsigned short* __restrict__ Qh, const unsigned short* __restrict__ Kh,
             const unsigned short* __restrict__ Vt, unsigned short* __restrict__ Out)
{
  __shared__ alignas(16) unsigned short Ks[64 * 128];
  __shared__ alignas(16) unsigned short Vs[128 * 64];
  __shared__ alignas(16) unsigned short Ps[4][1024];
  const int tid = threadIdx.x, lane = tid & 63, wid = tid >> 6;
  const int r = lane & 15, g = lane >> 4;
  const int sw = xcd_swizzle(blockIdx.y * gridDim.x + blockIdx.x, gridDim.x * gridDim.y);
  const int pair = sw % 16, bh = sw / 16;
  const int b = bh >> 4, h = bh & 15;
  const f32x4 zero = {0.f, 0.f, 0.f, 0.f};

  i32x4 kr[4], vr[4];
  auto issue_kv = [&](int kvt) {
    #pragma unroll
    for (int i = 0; i < 4; ++i) {
      const int c = i * 256 + tid;
      {
        const int row = c >> 4, slot = c & 15;
        kr[i] = *(const i32x4*)(Kh + ((size_t)bh * 2048 + kvt * 64 + row) * 128 + slot * 8);
      }
      {
        const int row = c >> 3, slot = c & 7;
        vr[i] = *(const i32x4*)(Vt + ((size_t)bh * 128 + row) * 2048 + kvt * 64 + slot * 8);
      }
    }
  };

  for (int half = 0; half < 2; ++half) {
    const int qt = half ? (31 - pair) : pair;
    const int qrow0 = qt * 64 + wid * 16;

    bf16x8 qf[4];
    {
      const unsigned short* qp = Qh + ((size_t)bh * 2048 + qrow0 + r) * 128;
      #pragma unroll
      for (int ks = 0; ks < 4; ++ks) qf[ks] = ld_frag(qp + ks * 32 + g * 8);
    }
    f32x4 oacc[8];
    #pragma unroll
    for (int i = 0; i < 8; ++i) oacc[i] = zero;
    float m_run[4] = {-1e30f, -1e30f, -1e30f, -1e30f};
    float l_run[4] = {0.f, 0.f, 0.f, 0.f};

    issue_kv(0);
    for (int kvt = 0; kvt <= qt; ++kvt) {
      __syncthreads();   // Ks/Vs free (prev compute done)
      #pragma unroll
      for (int i = 0; i < 4; ++i) {
        const int c = i * 256 + tid;
        {
          const int row = c >> 4, slot = c & 15;
          *(i32x4*)&Ks[row * 128 + ((slot ^ (row & 7)) << 3)] = kr[i];
        }
        {
          const int row = c >> 3, slot = c & 7;
          *(i32x4*)&Vs[row * 64 + ((slot ^ (row & 7)) << 3)] = vr[i];
        }
      }
      __syncthreads();
      if (kvt < qt) issue_kv(kvt + 1);   // loads fly under compute

      f32x4 sc[4];
      #pragma unroll
      for (int ni = 0; ni < 4; ++ni) sc[ni] = zero;
      __builtin_amdgcn_s_setprio(1);
      #pragma unroll
      for (int ks = 0; ks < 4; ++ks) {
        const int slot = (ks << 2) | g;
        #pragma unroll
        for (int ni = 0; ni < 4; ++ni) {
          const int krow = ni * 16 + r;
          bf16x8 kf = ld_frag(&Ks[krow * 128 + ((slot ^ (krow & 7)) << 3)]);
          sc[ni] = mfma16(qf[ks], kf, sc[ni]);
        }
      }
      __builtin_amdgcn_s_setprio(0);
      const float sscale = 0.08838834764831845f;   // 1/sqrt(128)
      if (kvt == qt) {
        #pragma unroll
        for (int ni = 0; ni < 4; ++ni) {
          const int kvg = kvt * 64 + ni * 16 + r;
          #pragma unroll
          for (int e = 0; e < 4; ++e) {
            const int qg = qrow0 + g * 4 + e;
            const float s = sc[ni][e] * sscale;
            sc[ni][e] = (kvg > qg) ? -1e30f : s;
          }
        }
      } else {
        #pragma unroll
        for (int ni = 0; ni < 4; ++ni) {
          #pragma unroll
          for (int e = 0; e < 4; ++e) sc[ni][e] *= sscale;
        }
      }
      float corr[4];
      #pragma unroll
      for (int e = 0; e < 4; ++e) {
        float mx = fmaxf(fmaxf(sc[0][e], sc[1][e]), fmaxf(sc[2][e], sc[3][e]));
        mx = fmaxf(mx, __shfl_xor(mx, 1));
        mx = fmaxf(mx, __shfl_xor(mx, 2));
        mx = fmaxf(mx, __shfl_xor(mx, 4));
        mx = fmaxf(mx, __shfl_xor(mx, 8));
        const float mn = fmaxf(m_run[e], mx);
        corr[e] = exp2f((m_run[e] - mn) * 1.4426950408889634f);
        m_run[e] = mn;
      }
      float psum[4] = {0.f, 0.f, 0.f, 0.f};
      #pragma unroll
      for (int ni = 0; ni < 4; ++ni) {
        #pragma unroll
        for (int e = 0; e < 4; ++e) {
          const float p = exp2f((sc[ni][e] - m_run[e]) * 1.4426950408889634f);
          sc[ni][e] = p;
          psum[e] += p;
        }
      }
      #pragma unroll
      for (int e = 0; e < 4; ++e) {
        float s = psum[e];
        s += __shfl_xor(s, 1);
        s += __shfl_xor(s, 2);
        s += __shfl_xor(s, 4);
        s += __shfl_xor(s, 8);
        l_run[e] = l_run[e] * corr[e] + s;
      }
      #pragma unroll
      for (int nf = 0; nf < 8; ++nf) {
        #pragma unroll
        for (int e = 0; e < 4; ++e) oacc[nf][e] *= corr[e];
      }
      #pragma unroll
      for (int ni = 0; ni < 4; ++ni) {
        #pragma unroll
        for (int e = 0; e < 4; ++e) {
          const int prow = g * 4 + e;
          const int col = ni * 16 + r;
          const int slot = col >> 3;
          Ps[wid][prow * 64 + ((slot ^ (prow & 7)) << 3) + (col & 7)] = f2bf_u(sc[ni][e]);
        }
      }
      __builtin_amdgcn_s_setprio(1);
      #pragma unroll
      for (int ks = 0; ks < 2; ++ks) {
        const int slot = (ks << 2) | g;
        bf16x8 pf = ld_frag(&Ps[wid][r * 64 + ((slot ^ (r & 7)) << 3)]);
        #pragma unroll
        for (int nf = 0; nf < 8; ++nf) {
          const int vrow = nf * 16 + r;
          bf16x8 vf = ld_frag(&Vs[vrow * 64 + ((slot ^ (vrow & 7)) << 3)]);
          oacc[nf] = mfma16(pf, vf, oacc[nf]);
        }
      }
      __builtin_amdgcn_s_setprio(0);
    }
    #pragma unroll
    for (int e = 0; e < 4; ++e) {
      const float inv = 1.f / l_run[e];
      const int qg = qrow0 + g * 4 + e;
      #pragma unroll
      for (int nf = 0; nf < 8; ++nf) {
        const int d = nf * 16 + r;
        Out[((size_t)(b * 2048 + qg)) * 2048 + h * 128 + d] = f2bf_u(oacc[nf][e] * inv);
      }
    }
  }
}

// ---------------------------------------------------------------------------
extern "C" void kernel_launch(void* const* d_in, const int* in_sizes, int n_in,
                              void* d_out, int out_size, void* d_ws, size_t ws_size,
                              hipStream_t stream)
{
  (void)in_sizes; (void)n_in; (void)out_size; (void)ws_size;
  const float* hid   = (const float*)d_in[0];
  const float* Wq    = (const float*)d_in[1];
  const float* bq    = (const float*)d_in[2];
  const float* Wk    = (const float*)d_in[3];
  const float* bk    = (const float*)d_in[4];
  const float* Wv    = (const float*)d_in[5];
  const float* bv    = (const float*)d_in[6];
  const float* Wo    = (const float*)d_in[7];
  const float* sq    = (const float*)d_in[8];
  const float* sk    = (const float*)d_in[9];
  const float* sv    = (const float*)d_in[10];
  const float* so    = (const float*)d_in[11];
  const float* permq = (const float*)d_in[12];
  const float* permo = (const float*)d_in[13];
  const int* pos     = (const int*)d_in[14];      // int32 per harness convention
  float* out = (float*)d_out;
  char* ws = (char*)d_ws;

  // ---- workspace layout (total ~178 MB) ----
  constexpr size_t OFF_ROWS = 0;                                   // 32KB
  constexpr size_t OFF_COLS = OFF_ROWS + (size_t)4 * 2048 * 4;     // 32KB
  constexpr size_t OFF_PART = OFF_COLS + (size_t)4 * 2048 * 4;     // 1MB
  constexpr size_t OFF_COS  = OFF_PART + (size_t)4 * 32 * 2048 * 4;
  constexpr size_t OFF_SIN  = OFF_COS + (size_t)2048 * 64 * 4;
  constexpr size_t SZ_PERM  = (size_t)2048 * 2048 * 2;             // 8MB
  constexpr size_t OFF_A    = OFF_SIN + (size_t)2048 * 64 * 4;     // 48MB region
  constexpr size_t OFF_PTQH = OFF_A;
  constexpr size_t OFF_PTQL = OFF_PTQH + SZ_PERM;
  constexpr size_t OFF_PTOH = OFF_PTQL + SZ_PERM;
  constexpr size_t OFF_PTOL = OFF_PTOH + SZ_PERM;
  constexpr size_t OFF_PBQ  = OFF_PTOL + SZ_PERM;
  constexpr size_t OFF_PBO  = OFF_PBQ + SZ_PERM;
  constexpr size_t SZ_M8    = (size_t)8192 * 2048 * 2;             // 32MB
  constexpr size_t OFF_B    = OFF_PBO + SZ_PERM;   // mhi   (later: yqkv spans B..C)
  constexpr size_t OFF_C    = OFF_B + SZ_M8;       // mlo
  constexpr size_t OFF_D    = OFF_C + SZ_M8;       // hard  (later: xbf @+0, att @+16MB)
  constexpr size_t OFF_E    = OFF_D + SZ_M8;       // wfin
  // END = OFF_E + SZ_M8 = 186,712,064 bytes

  float* rowsums = (float*)(ws + OFF_ROWS);
  float* colsums = (float*)(ws + OFF_COLS);
  float* part    = (float*)(ws + OFF_PART);
  float* cost    = (float*)(ws + OFF_COS);
  float* sint    = (float*)(ws + OFF_SIN);
  unsigned short* ptqh = (unsigned short*)(ws + OFF_PTQH);
  unsigned short* ptql = (unsigned short*)(ws + OFF_PTQL);
  unsigned short* ptoh = (unsigned short*)(ws + OFF_PTOH);
  unsigned short* ptol = (unsigned short*)(ws + OFF_PTOL);
  unsigned short* pbq  = (unsigned short*)(ws + OFF_PBQ);
  unsigned short* pbo  = (unsigned short*)(ws + OFF_PBO);
  unsigned short* mhi  = (unsigned short*)(ws + OFF_B);
  unsigned short* mlo  = (unsigned short*)(ws + OFF_C);
  unsigned short* hard = (unsigned short*)(ws + OFF_D);
  unsigned short* wfin = (unsigned short*)(ws + OFF_E);
  // aliases (lifetimes verified stage-by-stage):
  unsigned short* yqkv = (unsigned short*)(ws + OFF_B);            // 48MB of B..C
  unsigned short* qhb  = (unsigned short*)(ws + OFF_A);            // 16MB
  unsigned short* khb  = (unsigned short*)(ws + OFF_A + 2 * SZ_PERM);
  unsigned short* vtg  = (unsigned short*)(ws + OFF_A + 4 * SZ_PERM);
  unsigned short* xbf  = (unsigned short*)(ws + OFF_D);            // 16MB
  unsigned short* att  = (unsigned short*)(ws + OFF_D + SZ_M8 / 2);

  Ptr4 Wptrs{{Wq, Wk, Wv, Wo}};
  Ptr4 Sptrs{{sq, sk, sv, so}};
  Ptr4 BiasP{{bq, bk, bv, nullptr}};
  Ptr4 NoAux{{nullptr, nullptr, nullptr, nullptr}};
  constexpr int NOSW = 1 << 30;

  // 1) |W| sums
  k_rowsum<<<dim3(2048, 4), 256, 0, stream>>>(Wptrs, rowsums);
  k_colsum_part<<<dim3(8, 32, 4), 256, 0, stream>>>(Wptrs, part);
  k_colsum_red<<<32, 256, 0, stream>>>(part, colsums);
  // 2) metric (hi/lo split) for all 4 mats, stacked [8192][2048]
  k_metric<<<16384, 256, 0, stream>>>(Wptrs, Sptrs, rowsums, colsums, mhi, mlo);
  // 3) perm prep: transposed hi/lo split + fused plain bf16 cast
  k_perm_prep<<<dim3(32, 32, 2), 256, 0, stream>>>(permq, permo, ptqh, ptql, ptoh, ptol, pbq, pbo);
  // 4) hard = top2of4(metric @ perm)  — merged qkv+o launch, B switch at row 6144
  //    (no XCD swizzle: measured -8% on this kernel)
  gemm_bt<3, 1, 0><<<dim3(16, 64), 256, 0, stream>>>(mhi, mlo, ptqh, ptql, ptoh, ptol, 6144,
                                                     nullptr, hard, NoAux, 8192, 2048, 2048);
  // 5) Wfinal = W * (hard @ perm^T) — merged, aux p[row>>11] selects Wq..Wo
  gemm_bt<1, 0, 1><<<dim3(16, 64), 256, 0, stream>>>(hard, nullptr, pbq, nullptr, pbo, nullptr, 6144,
                                                     nullptr, wfin, Wptrs, 8192, 2048, 2048);
  // 6) x -> bf16 ; y_qkv = x @ Wfinal^T + bias (bf16, stacked N=6144)
  k_cast_bf<<<4096, 256, 0, stream>>>(hid, xbf);
  gemm_bt<2, 0, 1><<<dim3(48, 32), 256, 0, stream>>>(xbf, nullptr, wfin, nullptr, wfin, nullptr, NOSW,
                                                     nullptr, yqkv, BiasP, 4096, 6144, 2048);
  // 7) RoPE tables, q/k reshape+rope (vectorized), v transpose
  k_rope_tab<<<512, 256, 0, stream>>>(cost, sint);
  k_rope_reshape<<<4096, 256, 0, stream>>>(yqkv, pos, cost, sint, qhb, khb);
  k_vtrans<<<dim3(32, 32), 256, 0, stream>>>(yqkv, vtg);
  // 8) flash attention (paired q-tiles, pipelined K/V loads, XCD swizzle)
  attn_fa<<<dim3(16, 32), 256, 0, stream>>>(qhb, khb, vtg, att);
  // 9) out = attn @ Wo_final^T (f32)
  gemm_bt<0, 0, 1><<<dim3(16, 32), 256, 0, stream>>>(att, nullptr, wfin + (size_t)6144 * 2048, nullptr,
                                                     wfin + (size_t)6144 * 2048, nullptr, NOSW,
                                                     out, nullptr, NoAux, 4096, 2048, 2048);
}

// Round 10
// 637.454 us; speedup vs baseline: 1.0340x; 1.0175x over previous
//
#include <hip/hip_runtime.h>
#include <cstdint>
#include <cstddef>

typedef __attribute__((ext_vector_type(4))) float  f32x4;
typedef __attribute__((ext_vector_type(4))) int    i32x4;
typedef __attribute__((ext_vector_type(8))) short  s16x8;
typedef __attribute__((ext_vector_type(4))) short  s16x4;
typedef __attribute__((ext_vector_type(8))) __bf16 bf16x8;

struct Ptr4 { const float* p[4]; };

#define DEV __device__ __forceinline__

DEV unsigned short f2bf_u(float x) {
  unsigned u = __builtin_bit_cast(unsigned, x);
  u += 0x7fffu + ((u >> 16) & 1u);
  return (unsigned short)(u >> 16);
}
DEV float bfu2f(unsigned short u) {
  return __builtin_bit_cast(float, ((unsigned)u) << 16);
}
DEV bf16x8 ld_frag(const unsigned short* p) {
  s16x8 v = *(const s16x8*)p;
  return __builtin_bit_cast(bf16x8, v);
}
DEV f32x4 mfma16(bf16x8 a, bf16x8 b, f32x4 c) {
  return __builtin_amdgcn_mfma_f32_16x16x32_bf16(a, b, c, 0, 0, 0);
}
// async global->LDS, 16B per lane; LDS dest = wave-uniform base + lane*16
DEV void gload_lds16(const unsigned short* g, unsigned short* l) {
  __builtin_amdgcn_global_load_lds(
      (const __attribute__((address_space(1))) unsigned int*)g,
      (__attribute__((address_space(3))) unsigned int*)l, 16, 0, 0);
}
// XCD-chunked bijective block-id swizzle (requires nwg % 8 == 0).
// Measured (r5/r7/r8 A/B): helps attention and the non-split GEMMs; HURTS
// the split GEMM. Applied selectively via template flag.
DEV int xcd_swizzle(int bid, int nwg) {
  const int q8 = nwg >> 3;
  return (bid & 7) * q8 + (bid >> 3);
}

// ---------------------------------------------------------------------------
// |W| row sums (one block per row, deterministic)
// ---------------------------------------------------------------------------
__global__ __launch_bounds__(256)
void k_rowsum(Ptr4 Ws, float* __restrict__ rowsums)
{
  const int row = blockIdx.x, mat = blockIdx.y, tid = threadIdx.x;
  const float* W = Ws.p[mat] + (size_t)row * 2048;
  float s = 0.f;
  #pragma unroll
  for (int p = 0; p < 2; ++p) {
    f32x4 v = *(const f32x4*)(W + p * 1024 + tid * 4);
    s += fabsf(v[0]) + fabsf(v[1]) + fabsf(v[2]) + fabsf(v[3]);
  }
  #pragma unroll
  for (int off = 1; off < 64; off <<= 1) s += __shfl_xor(s, off);
  __shared__ float red[4];
  if ((tid & 63) == 0) red[tid >> 6] = s;
  __syncthreads();
  if (tid == 0) rowsums[mat * 2048 + row] = red[0] + red[1] + red[2] + red[3];
}

// |W| column sums: partial over 64-row stripes, then reduce (no atomics)
__global__ __launch_bounds__(256)
void k_colsum_part(Ptr4 Ws, float* __restrict__ part)
{
  const int c = blockIdx.x * 256 + threadIdx.x;
  const int r0 = blockIdx.y * 64;
  const int mat = blockIdx.z;
  const float* W = Ws.p[mat];
  float s = 0.f;
  for (int rr = 0; rr < 64; ++rr) s += fabsf(W[(size_t)(r0 + rr) * 2048 + c]);
  part[((size_t)mat * 32 + blockIdx.y) * 2048 + c] = s;
}
__global__ __launch_bounds__(256)
void k_colsum_red(const float* __restrict__ part, float* __restrict__ colsums)
{
  const int gid = blockIdx.x * 256 + threadIdx.x;   // 4*2048
  const int mat = gid >> 11, c = gid & 2047;
  float s = 0.f;
  #pragma unroll
  for (int j = 0; j < 32; ++j) s += part[((size_t)mat * 32 + j) * 2048 + c];
  colsums[gid] = s;
}

// metric[r,c] = |W|*(1/colsum[c] + 1/rowsum[r]) * sqrt(scaler[c]) ; hi/lo bf16 split
__global__ __launch_bounds__(256)
void k_metric(Ptr4 Ws, Ptr4 Ss, const float* __restrict__ rowsums,
              const float* __restrict__ colsums,
              unsigned short* __restrict__ mhi, unsigned short* __restrict__ mlo)
{
  const size_t idx4 = ((size_t)blockIdx.x * 256 + threadIdx.x) * 4;
  const int row = (int)(idx4 >> 11);
  const int c = (int)(idx4 & 2047);
  const int mat = row >> 11, rl = row & 2047;
  const float rs = rowsums[mat * 2048 + rl];
  f32x4 w  = *(const f32x4*)(Ws.p[mat] + (size_t)rl * 2048 + c);
  f32x4 cs = *(const f32x4*)(colsums + mat * 2048 + c);
  f32x4 sv = *(const f32x4*)(Ss.p[mat] + c);
  s16x4 hv, lv;
  #pragma unroll
  for (int j = 0; j < 4; ++j) {
    const float a = fabsf(w[j]);
    const float m = (a / cs[j] + a / rs) * sqrtf(sv[j]);
    const unsigned short hb = f2bf_u(m);
    hv[j] = (short)hb;
    lv[j] = (short)f2bf_u(m - bfu2f(hb));
  }
  *(s16x4*)(mhi + idx4) = hv;
  *(s16x4*)(mlo + idx4) = lv;
}

// perm -> permT hi/lo bf16 (tiled transpose) + fused plain bf16 cast
__global__ __launch_bounds__(256)
void k_perm_prep(const float* __restrict__ pq, const float* __restrict__ po,
                 unsigned short* __restrict__ thi_q, unsigned short* __restrict__ tlo_q,
                 unsigned short* __restrict__ thi_o, unsigned short* __restrict__ tlo_o,
                 unsigned short* __restrict__ pb_q, unsigned short* __restrict__ pb_o)
{
  __shared__ float T[64 * 65];
  const int which = blockIdx.z;
  const float* src = which ? po : pq;
  unsigned short* thi = which ? thi_o : thi_q;
  unsigned short* tlo = which ? tlo_o : tlo_q;
  unsigned short* pb  = which ? pb_o : pb_q;
  const int rb = blockIdx.y * 64, cb = blockIdx.x * 64, tid = threadIdx.x;
  #pragma unroll
  for (int i = 0; i < 4; ++i) {
    const int cc = i * 256 + tid;
    const int rowl = cc >> 4, c4 = (cc & 15) * 4;
    f32x4 v = *(const f32x4*)(src + (size_t)(rb + rowl) * 2048 + cb + c4);
    s16x4 pc;
    #pragma unroll
    for (int j = 0; j < 4; ++j) {
      T[rowl * 65 + c4 + j] = v[j];
      pc[j] = (short)f2bf_u(v[j]);
    }
    *(s16x4*)(pb + (size_t)(rb + rowl) * 2048 + cb + c4) = pc;
  }
  __syncthreads();
  #pragma unroll
  for (int i = 0; i < 4; ++i) {
    const int cc = i * 256 + tid;
    const int rowt = cc >> 4, c4 = (cc & 15) * 4;
    s16x4 hh, ll;
    #pragma unroll
    for (int j = 0; j < 4; ++j) {
      const float v = T[(c4 + j) * 65 + rowt];
      const unsigned short hb = f2bf_u(v);
      hh[j] = (short)hb;
      ll[j] = (short)f2bf_u(v - bfu2f(hb));
    }
    const size_t off = (size_t)(cb + rowt) * 2048 + rb + c4;
    *(s16x4*)(thi + off) = hh;
    *(s16x4*)(tlo + off) = ll;
  }
}

// plain f32 -> bf16 cast (8 elems/thread)
__global__ __launch_bounds__(256)
void k_cast_bf(const float* __restrict__ src, unsigned short* __restrict__ dst)
{
  const size_t i = ((size_t)blockIdx.x * 256 + threadIdx.x) * 8;
  f32x4 a = *(const f32x4*)(src + i);
  f32x4 b = *(const f32x4*)(src + i + 4);
  s16x8 o;
  #pragma unroll
  for (int j = 0; j < 4; ++j) o[j] = (short)f2bf_u(a[j]);
  #pragma unroll
  for (int j = 0; j < 4; ++j) o[4 + j] = (short)f2bf_u(b[j]);
  *(s16x8*)(dst + i) = o;
}

// RoPE tables [2048][64]
__global__ __launch_bounds__(256)
void k_rope_tab(float* __restrict__ ct, float* __restrict__ st)
{
  const int gid = blockIdx.x * 256 + threadIdx.x;
  const int s = gid >> 6, i = gid & 63;
  const float ex = (float)(2 * i) / 128.f;
  const float inv = 1.f / powf(10000.f, ex);
  const float f = (float)s * inv;
  ct[gid] = cosf(f);
  st[gid] = sinf(f);
}

// y_qkv [4096][6144] -> q,k head-major [2][16][2048][128] with RoPE.
// Pair-fused: one thread = chunks d8p and d8p+8 (the RoPE partner pair) ->
// each y-chunk loaded exactly once (reads halved vs r9), outputs bit-identical.
__global__ __launch_bounds__(256)
void k_rope_reshape(const unsigned short* __restrict__ yqkv, const int* __restrict__ pos,
                    const float* __restrict__ ct, const float* __restrict__ st,
                    unsigned short* __restrict__ qo, unsigned short* __restrict__ ko)
{
  const int gid = blockIdx.x * 256 + threadIdx.x;   // 2*16*2048*8 pairs
  const int d8p = gid & 7;
  const int s = (gid >> 3) & 2047;
  const int h = (gid >> 14) & 15;
  const int b = gid >> 18;
  const int t = b * 2048 + s;
  const int p = pos[t];
  const size_t yb = (size_t)t * 6144 + h * 128;
  s16x8 qa = *(const s16x8*)(yqkv + yb + d8p * 8);
  s16x8 qb = *(const s16x8*)(yqkv + yb + (d8p + 8) * 8);
  s16x8 ka = *(const s16x8*)(yqkv + yb + 2048 + d8p * 8);
  s16x8 kb = *(const s16x8*)(yqkv + yb + 2048 + (d8p + 8) * 8);
  const int dh0 = d8p * 8;
  s16x8 qoa, qob, koa, kob;
  #pragma unroll
  for (int j = 0; j < 8; ++j) {
    const float cv = ct[p * 64 + dh0 + j];
    const float sv = st[p * 64 + dh0 + j];
    const float qav = bfu2f((unsigned short)qa[j]);
    const float qbv = bfu2f((unsigned short)qb[j]);
    const float kav = bfu2f((unsigned short)ka[j]);
    const float kbv = bfu2f((unsigned short)kb[j]);
    qoa[j] = (short)f2bf_u(qav * cv + (-1.f * qbv) * sv);   // lower half: sgn=-1
    koa[j] = (short)f2bf_u(kav * cv + (-1.f * kbv) * sv);
    qob[j] = (short)f2bf_u(qbv * cv + qav * sv);            // upper half: sgn=+1
    kob[j] = (short)f2bf_u(kbv * cv + kav * sv);
  }
  const size_t o = ((size_t)(b * 16 + h) * 2048 + s) * 128 + d8p * 8;
  *(s16x8*)(qo + o) = qoa;
  *(s16x8*)(qo + o + 64) = qob;
  *(s16x8*)(ko + o) = koa;
  *(s16x8*)(ko + o + 64) = kob;
}

// y_qkv v-part -> Vt global [2][16][128][2048] (LDS-tiled transpose)
__global__ __launch_bounds__(256)
void k_vtrans(const unsigned short* __restrict__ yqkv, unsigned short* __restrict__ vt)
{
  __shared__ float T[64 * 129];
  const int st = blockIdx.x, bh = blockIdx.y, tid = threadIdx.x;
  const int b = bh >> 4, h = bh & 15;
  #pragma unroll
  for (int i = 0; i < 4; ++i) {
    const int c = i * 256 + tid;           // 0..1023
    const int sl = c >> 4, d8 = (c & 15) * 8;
    s16x8 v = *(const s16x8*)(yqkv + (size_t)(b * 2048 + st * 64 + sl) * 6144 + 4096 + h * 128 + d8);
    #pragma unroll
    for (int j = 0; j < 8; ++j) T[sl * 129 + d8 + j] = bfu2f((unsigned short)v[j]);
  }
  __syncthreads();
  #pragma unroll
  for (int i = 0; i < 4; ++i) {
    const int c = i * 256 + tid;
    const int d = c >> 3, s8 = (c & 7) * 8;
    s16x8 o;
    #pragma unroll
    for (int j = 0; j < 8; ++j) o[j] = (short)f2bf_u(T[(s8 + j) * 129 + d]);
    *(s16x8*)(vt + ((size_t)bh * 128 + d) * 2048 + st * 64 + s8) = o;
  }
}

// ---------------------------------------------------------------------------
// Generic bf16 MFMA GEMM, C[M,N] = A[M,K] @ B[N,K]^T, 128x128 tile.
// SPLIT=1: BK=64, single-buffer hi/lo planes (64KB LDS), TWO barriers per
//   64-K (half of r5's four): barrier -> slice0 reads+MFMA + slice1 reads ->
//   barrier -> issue next tile -> slice1 MFMA. Same accumulation order as r5
//   (two consecutive 32-K steps) -> bit-identical output. LDS layout
//   [row][64k], XOR swizzle chunk ^= row&7 on both staging source and reads.
// SPLIT=0: BK=32 double-buffered (32KB), ONE barrier per K-step (r9 best).
// SWZ: XCD-chunked block swizzle (non-split GEMMs only; hurts split, r5/r7).
// MODE 0: Cf = acc (f32).
// MODE 1: Cb = bf16(acc * aux.p[row>>11][row&2047, col]).
// MODE 2: Cb = bf16(acc + aux.p[col>>11][col&2047]).
// MODE 3: fused top-2-of-4 over col blocks -> Cb in {bf16 1.0, 0.0}.
// SPLIT: A,B given as hi/lo bf16 pairs; acc = Al*Bh + Ah*Bl + Ah*Bh.
// ---------------------------------------------------------------------------
template<int MODE, int SPLIT, int SWZ>
__global__ __launch_bounds__(256)
void gemm_bt(const unsigned short* __restrict__ Ahi, const unsigned short* __restrict__ Alo,
             const unsigned short* __restrict__ Bhi_1, const unsigned short* __restrict__ Blo_1,
             const unsigned short* __restrict__ Bhi_2, const unsigned short* __restrict__ Blo_2,
             int bswitch,
             float* __restrict__ Cf, unsigned short* __restrict__ Cb,
             Ptr4 aux, int M, int N, int K)
{
  // SPLIT: hi plane [0,8192), lo plane [8192,16384) ushorts ([128][64] each).
  // non-SPLIT: buf0 [0,4096), buf1 [4096,8192) ([128][32] each).
  __shared__ alignas(16) unsigned short As[(SPLIT ? 4 : 2) * 4096];
  __shared__ alignas(16) unsigned short Bs[(SPLIT ? 4 : 2) * 4096];
  const int tid = threadIdx.x;
  const int lane = tid & 63, wid = tid >> 6;
  const int wm = wid >> 1, wn = wid & 1;
  const int r = lane & 15, g = lane >> 4;
  int bx = blockIdx.x, by = blockIdx.y;
  if (SWZ) {
    const int nwg = gridDim.x * gridDim.y;
    const int sw = xcd_swizzle(blockIdx.y * gridDim.x + blockIdx.x, nwg);
    bx = sw % gridDim.x; by = sw / gridDim.x;
  }
  const int mbase = by * 128;
  const int nbase = bx * 128;
  (void)M;
  const unsigned short* Bhi = (mbase >= bswitch) ? Bhi_2 : Bhi_1;
  const unsigned short* Blo = (mbase >= bswitch) ? Blo_2 : Blo_1;

  const f32x4 zero = {0.f, 0.f, 0.f, 0.f};
  f32x4 acc[4][4];
  #pragma unroll
  for (int i = 0; i < 4; ++i) {
    #pragma unroll
    for (int j = 0; j < 4; ++j) acc[i][j] = zero;
  }

  if (SPLIT) {
    // ---- BK=64 single-buffer path ----
    const int KT = K >> 6;
    const int srl = lane >> 3;          // row within 8-row issue group
    const int sch = lane & 7;           // 16B chunk within 64-elem row
    // LDS[row][c] holds global chunk c ^ (row&7); row&7 == srl (rbase%8==0).
    auto issue_tile = [&](int kt) {
      const size_t kb = (size_t)kt * 64;
      #pragma unroll
      for (int i = 0; i < 4; ++i) {
        const int rbase = wid * 32 + i * 8;
        const int rloc = rbase + srl;
        const int cs = (sch ^ srl) * 8;
        const size_t ga = (size_t)(mbase + rloc) * K + kb + cs;
        const size_t gb = (size_t)(nbase + rloc) * K + kb + cs;
        gload_lds16(Ahi + ga, &As[rbase * 64]);
        gload_lds16(Alo + ga, &As[8192 + rbase * 64]);
        gload_lds16(Bhi + gb, &Bs[rbase * 64]);
        gload_lds16(Blo + gb, &Bs[8192 + rbase * 64]);
      }
    };
    auto do_slice = [&](int ks) {
      bf16x8 ah[4], al[4], bfr[4], bl[4];
      #pragma unroll
      for (int mi = 0; mi < 4; ++mi) {
        const int arow = wm * 64 + mi * 16 + r;
        const int co = (((ks * 4 + g) ^ (arow & 7)) << 3);
        ah[mi] = ld_frag(&As[arow * 64 + co]);
        al[mi] = ld_frag(&As[8192 + arow * 64 + co]);
      }
      #pragma unroll
      for (int ni = 0; ni < 4; ++ni) {
        const int brow = wn * 64 + ni * 16 + r;
        const int co = (((ks * 4 + g) ^ (brow & 7)) << 3);
        bfr[ni] = ld_frag(&Bs[brow * 64 + co]);
        bl[ni] = ld_frag(&Bs[8192 + brow * 64 + co]);
      }
      #pragma unroll
      for (int mi = 0; mi < 4; ++mi) {
        #pragma unroll
        for (int ni = 0; ni < 4; ++ni) {
          acc[mi][ni] = mfma16(al[mi], bfr[ni], acc[mi][ni]);
          acc[mi][ni] = mfma16(ah[mi], bl[ni], acc[mi][ni]);
          acc[mi][ni] = mfma16(ah[mi], bfr[ni], acc[mi][ni]);
        }
      }
    };

    issue_tile(0);
    for (int kt = 0; kt < KT; ++kt) {
      __syncthreads();          // tile staged (vmcnt drained before barrier)
      // slice 0: read frags + MFMA; then pre-read slice-1 frags.
      bf16x8 ah1[4], al1[4], bfr1[4], bl1[4];
      {
        bf16x8 ah[4], al[4], bfr[4], bl[4];
        #pragma unroll
        for (int mi = 0; mi < 4; ++mi) {
          const int arow = wm * 64 + mi * 16 + r;
          const int co = ((g ^ (arow & 7)) << 3);
          ah[mi] = ld_frag(&As[arow * 64 + co]);
          al[mi] = ld_frag(&As[8192 + arow * 64 + co]);
        }
        #pragma unroll
        for (int ni = 0; ni < 4; ++ni) {
          const int brow = wn * 64 + ni * 16 + r;
          const int co = ((g ^ (brow & 7)) << 3);
          bfr[ni] = ld_frag(&Bs[brow * 64 + co]);
          bl[ni] = ld_frag(&Bs[8192 + brow * 64 + co]);
        }
        #pragma unroll
        for (int mi = 0; mi < 4; ++mi) {
          #pragma unroll
          for (int ni = 0; ni < 4; ++ni) {
            acc[mi][ni] = mfma16(al[mi], bfr[ni], acc[mi][ni]);
            acc[mi][ni] = mfma16(ah[mi], bl[ni], acc[mi][ni]);
            acc[mi][ni] = mfma16(ah[mi], bfr[ni], acc[mi][ni]);
          }
        }
      }
      #pragma unroll
      for (int mi = 0; mi < 4; ++mi) {
        const int arow = wm * 64 + mi * 16 + r;
        const int co = (((4 + g) ^ (arow & 7)) << 3);
        ah1[mi] = ld_frag(&As[arow * 64 + co]);
        al1[mi] = ld_frag(&As[8192 + arow * 64 + co]);
      }
      #pragma unroll
      for (int ni = 0; ni < 4; ++ni) {
        const int brow = wn * 64 + ni * 16 + r;
        const int co = (((4 + g) ^ (brow & 7)) << 3);
        bfr1[ni] = ld_frag(&Bs[brow * 64 + co]);
        bl1[ni] = ld_frag(&Bs[8192 + brow * 64 + co]);
      }
      __syncthreads();          // all waves done reading this tile
      if (kt + 1 < KT) issue_tile(kt + 1);   // loads fly under slice-1 MFMAs
      #pragma unroll
      for (int mi = 0; mi < 4; ++mi) {
        #pragma unroll
        for (int ni = 0; ni < 4; ++ni) {
          acc[mi][ni] = mfma16(al1[mi], bfr1[ni], acc[mi][ni]);
          acc[mi][ni] = mfma16(ah1[mi], bl1[ni], acc[mi][ni]);
          acc[mi][ni] = mfma16(ah1[mi], bfr1[ni], acc[mi][ni]);
        }
      }
    }
    (void)do_slice;
  } else {
    // ---- BK=32 double-buffer path (r9-proven) ----
    const int KT = K >> 5;
    const int srl = lane >> 2;
    const int sch = lane & 3;
    auto issue_tile = [&](int kt, int buf) {
      const size_t kb = (size_t)kt * 32;
      #pragma unroll
      for (int i = 0; i < 2; ++i) {
        const int rbase = wid * 32 + i * 16;
        const int rloc = rbase + srl;
        const int sc = ((sch ^ ((rloc >> 1) & 3)) << 3);
        const size_t ga = (size_t)(mbase + rloc) * K + kb + sc;
        const size_t gb = (size_t)(nbase + rloc) * K + kb + sc;
        gload_lds16(Ahi + ga, &As[buf * 4096 + rbase * 32]);
        gload_lds16(Bhi + gb, &Bs[buf * 4096 + rbase * 32]);
      }
    };
    issue_tile(0, 0);
    int cur = 0;
    for (int kt = 0; kt < KT; ++kt) {
      __syncthreads();   // buf[cur] staged; prior readers of buf[cur^1] done
      if (kt + 1 < KT) issue_tile(kt + 1, cur ^ 1);  // overlap ds_read + MFMA
      bf16x8 ah[4], bfr[4];
      #pragma unroll
      for (int mi = 0; mi < 4; ++mi) {
        const int arow = wm * 64 + mi * 16 + r;
        ah[mi] = ld_frag(&As[cur * 4096 + arow * 32 + ((g ^ ((arow >> 1) & 3)) << 3)]);
      }
      #pragma unroll
      for (int ni = 0; ni < 4; ++ni) {
        const int brow = wn * 64 + ni * 16 + r;
        bfr[ni] = ld_frag(&Bs[cur * 4096 + brow * 32 + ((g ^ ((brow >> 1) & 3)) << 3)]);
      }
      #pragma unroll
      for (int mi = 0; mi < 4; ++mi) {
        #pragma unroll
        for (int ni = 0; ni < 4; ++ni)
          acc[mi][ni] = mfma16(ah[mi], bfr[ni], acc[mi][ni]);
      }
      cur ^= 1;
    }
  }

  #pragma unroll
  for (int mi = 0; mi < 4; ++mi) {
    #pragma unroll
    for (int ni = 0; ni < 4; ++ni) {
      const int row0 = mbase + wm * 64 + mi * 16 + g * 4;
      const int col  = nbase + wn * 64 + ni * 16 + r;
      if (MODE == 0) {
        #pragma unroll
        for (int e = 0; e < 4; ++e)
          Cf[(size_t)(row0 + e) * N + col] = acc[mi][ni][e];
      } else if (MODE == 1) {
        const float* wsrc = aux.p[row0 >> 11];
        #pragma unroll
        for (int e = 0; e < 4; ++e) {
          const float mval = wsrc[(size_t)((row0 + e) & 2047) * 2048 + col];
          Cb[(size_t)(row0 + e) * N + col] = f2bf_u(acc[mi][ni][e] * mval);
        }
      } else if (MODE == 2) {
        const float* bp = aux.p[col >> 11];
        const float bb = bp[col & 2047];
        #pragma unroll
        for (int e = 0; e < 4; ++e)
          Cb[(size_t)(row0 + e) * N + col] = f2bf_u(acc[mi][ni][e] + bb);
      } else {
        // MODE 3: top-2-of-4 across the 4-col block; partners live in lanes
        // r^1, r^2, r^3 (same g). Rank by (value desc, index asc).
        const int ii = r & 3;
        #pragma unroll
        for (int e = 0; e < 4; ++e) {
          const float v  = acc[mi][ni][e];
          const float v1 = __shfl_xor(v, 1);
          const float v2 = __shfl_xor(v, 2);
          const float v3 = __shfl_xor(v, 3);
          int cnt = 0;
          { const int j = ii ^ 1; cnt += (v1 > v) || (v1 == v && j < ii); }
          { const int j = ii ^ 2; cnt += (v2 > v) || (v2 == v && j < ii); }
          { const int j = ii ^ 3; cnt += (v3 > v) || (v3 == v && j < ii); }
          Cb[(size_t)(row0 + e) * N + col] =
              (cnt < 2) ? (unsigned short)0x3F80 : (unsigned short)0;
        }
      }
    }
  }
}

// ---------------------------------------------------------------------------
// Flash attention: 512 blocks; XCD-chunked swizzle keeps 4 consecutive bh
// (4 MB K/V = one XCD's L2) per XCD. Block processes q-tiles {pair, 31-pair}
// sequentially -> uniform 33 KV-iterations. 4 waves x 16 q-rows, KBLK=64.
// K/V loads for kvt+1 issued right after the write-barrier (latency hiding).
// setprio(1) around MFMA clusters (T5, attn-positive).
// Q [bh][s][128], K [bh][s][128], Vt [bh][128][s]; Out token-major [4096][2048].
// ---------------------------------------------------------------------------
__global__ __launch_bounds__(256)
void attn_fa(const unsigned short* __restrict__ Qh, const unsigned short* __restrict__ Kh,
             const unsigned short* __restrict__ Vt, unsigned short* __restrict__ Out)
{
  __shared__ alignas(16) unsigned short Ks[64 * 128];
  __shared__ alignas(16) unsigned short Vs[128 * 64];
  __shared__ alignas(16) unsigned short Ps[4][1024];
  const int tid = threadIdx.x, lane = tid & 63, wid = tid >> 6;
  const int r = lane & 15, g = lane >> 4;
  const int sw = xcd_swizzle(blockIdx.y * gridDim.x + blockIdx.x, gridDim.x * gridDim.y);
  const int pair = sw % 16, bh = sw / 16;
  const int b = bh >> 4, h = bh & 15;
  const f32x4 zero = {0.f, 0.f, 0.f, 0.f};

  i32x4 kr[4], vr[4];
  auto issue_kv = [&](int kvt) {
    #pragma unroll
    for (int i = 0; i < 4; ++i) {
      const int c = i * 256 + tid;
      {
        const int row = c >> 4, slot = c & 15;
        kr[i] = *(const i32x4*)(Kh + ((size_t)bh * 2048 + kvt * 64 + row) * 128 + slot * 8);
      }
      {
        const int row = c >> 3, slot = c & 7;
        vr[i] = *(const i32x4*)(Vt + ((size_t)bh * 128 + row) * 2048 + kvt * 64 + slot * 8);
      }
    }
  };

  for (int half = 0; half < 2; ++half) {
    const int qt = half ? (31 - pair) : pair;
    const int qrow0 = qt * 64 + wid * 16;

    bf16x8 qf[4];
    {
      const unsigned short* qp = Qh + ((size_t)bh * 2048 + qrow0 + r) * 128;
      #pragma unroll
      for (int ks = 0; ks < 4; ++ks) qf[ks] = ld_frag(qp + ks * 32 + g * 8);
    }
    f32x4 oacc[8];
    #pragma unroll
    for (int i = 0; i < 8; ++i) oacc[i] = zero;
    float m_run[4] = {-1e30f, -1e30f, -1e30f, -1e30f};
    float l_run[4] = {0.f, 0.f, 0.f, 0.f};

    issue_kv(0);
    for (int kvt = 0; kvt <= qt; ++kvt) {
      __syncthreads();   // Ks/Vs free (prev compute done)
      #pragma unroll
      for (int i = 0; i < 4; ++i) {
        const int c = i * 256 + tid;
        {
          const int row = c >> 4, slot = c & 15;
          *(i32x4*)&Ks[row * 128 + ((slot ^ (row & 7)) << 3)] = kr[i];
        }
        {
          const int row = c >> 3, slot = c & 7;
          *(i32x4*)&Vs[row * 64 + ((slot ^ (row & 7)) << 3)] = vr[i];
        }
      }
      __syncthreads();
      if (kvt < qt) issue_kv(kvt + 1);   // loads fly under compute

      f32x4 sc[4];
      #pragma unroll
      for (int ni = 0; ni < 4; ++ni) sc[ni] = zero;
      __builtin_amdgcn_s_setprio(1);
      #pragma unroll
      for (int ks = 0; ks < 4; ++ks) {
        const int slot = (ks << 2) | g;
        #pragma unroll
        for (int ni = 0; ni < 4; ++ni) {
          const int krow = ni * 16 + r;
          bf16x8 kf = ld_frag(&Ks[krow * 128 + ((slot ^ (krow & 7)) << 3)]);
          sc[ni] = mfma16(qf[ks], kf, sc[ni]);
        }
      }
      __builtin_amdgcn_s_setprio(0);
      const float sscale = 0.08838834764831845f;   // 1/sqrt(128)
      if (kvt == qt) {
        #pragma unroll
        for (int ni = 0; ni < 4; ++ni) {
          const int kvg = kvt * 64 + ni * 16 + r;
          #pragma unroll
          for (int e = 0; e < 4; ++e) {
            const int qg = qrow0 + g * 4 + e;
            const float s = sc[ni][e] * sscale;
            sc[ni][e] = (kvg > qg) ? -1e30f : s;
          }
        }
      } else {
        #pragma unroll
        for (int ni = 0; ni < 4; ++ni) {
          #pragma unroll
          for (int e = 0; e < 4; ++e) sc[ni][e] *= sscale;
        }
      }
      float corr[4];
      #pragma unroll
      for (int e = 0; e < 4; ++e) {
        float mx = fmaxf(fmaxf(sc[0][e], sc[1][e]), fmaxf(sc[2][e], sc[3][e]));
        mx = fmaxf(mx, __shfl_xor(mx, 1));
        mx = fmaxf(mx, __shfl_xor(mx, 2));
        mx = fmaxf(mx, __shfl_xor(mx, 4));
        mx = fmaxf(mx, __shfl_xor(mx, 8));
        const float mn = fmaxf(m_run[e], mx);
        corr[e] = exp2f((m_run[e] - mn) * 1.4426950408889634f);
        m_run[e] = mn;
      }
      float psum[4] = {0.f, 0.f, 0.f, 0.f};
      #pragma unroll
      for (int ni = 0; ni < 4; ++ni) {
        #pragma unroll
        for (int e = 0; e < 4; ++e) {
          const float p = exp2f((sc[ni][e] - m_run[e]) * 1.4426950408889634f);
          sc[ni][e] = p;
          psum[e] += p;
        }
      }
      #pragma unroll
      for (int e = 0; e < 4; ++e) {
        float s = psum[e];
        s += __shfl_xor(s, 1);
        s += __shfl_xor(s, 2);
        s += __shfl_xor(s, 4);
        s += __shfl_xor(s, 8);
        l_run[e] = l_run[e] * corr[e] + s;
      }
      #pragma unroll
      for (int nf = 0; nf < 8; ++nf) {
        #pragma unroll
        for (int e = 0; e < 4; ++e) oacc[nf][e] *= corr[e];
      }
      #pragma unroll
      for (int ni = 0; ni < 4; ++ni) {
        #pragma unroll
        for (int e = 0; e < 4; ++e) {
          const int prow = g * 4 + e;
          const int col = ni * 16 + r;
          const int slot = col >> 3;
          Ps[wid][prow * 64 + ((slot ^ (prow & 7)) << 3) + (col & 7)] = f2bf_u(sc[ni][e]);
        }
      }
      __builtin_amdgcn_s_setprio(1);
      #pragma unroll
      for (int ks = 0; ks < 2; ++ks) {
        const int slot = (ks << 2) | g;
        bf16x8 pf = ld_frag(&Ps[wid][r * 64 + ((slot ^ (r & 7)) << 3)]);
        #pragma unroll
        for (int nf = 0; nf < 8; ++nf) {
          const int vrow = nf * 16 + r;
          bf16x8 vf = ld_frag(&Vs[vrow * 64 + ((slot ^ (vrow & 7)) << 3)]);
          oacc[nf] = mfma16(pf, vf, oacc[nf]);
        }
      }
      __builtin_amdgcn_s_setprio(0);
    }
    #pragma unroll
    for (int e = 0; e < 4; ++e) {
      const float inv = 1.f / l_run[e];
      const int qg = qrow0 + g * 4 + e;
      #pragma unroll
      for (int nf = 0; nf < 8; ++nf) {
        const int d = nf * 16 + r;
        Out[((size_t)(b * 2048 + qg)) * 2048 + h * 128 + d] = f2bf_u(oacc[nf][e] * inv);
      }
    }
  }
}

// ---------------------------------------------------------------------------
extern "C" void kernel_launch(void* const* d_in, const int* in_sizes, int n_in,
                              void* d_out, int out_size, void* d_ws, size_t ws_size,
                              hipStream_t stream)
{
  (void)in_sizes; (void)n_in; (void)out_size; (void)ws_size;
  const float* hid   = (const float*)d_in[0];
  const float* Wq    = (const float*)d_in[1];
  const float* bq    = (const float*)d_in[2];
  const float* Wk    = (const float*)d_in[3];
  const float* bk    = (const float*)d_in[4];
  const float* Wv    = (const float*)d_in[5];
  const float* bv    = (const float*)d_in[6];
  const float* Wo    = (const float*)d_in[7];
  const float* sq    = (const float*)d_in[8];
  const float* sk    = (const float*)d_in[9];
  const float* sv    = (const float*)d_in[10];
  const float* so    = (const float*)d_in[11];
  const float* permq = (const float*)d_in[12];
  const float* permo = (const float*)d_in[13];
  const int* pos     = (const int*)d_in[14];      // int32 per harness convention
  float* out = (float*)d_out;
  char* ws = (char*)d_ws;

  // ---- workspace layout (total ~178 MB) ----
  constexpr size_t OFF_ROWS = 0;                                   // 32KB
  constexpr size_t OFF_COLS = OFF_ROWS + (size_t)4 * 2048 * 4;     // 32KB
  constexpr size_t OFF_PART = OFF_COLS + (size_t)4 * 2048 * 4;     // 1MB
  constexpr size_t OFF_COS  = OFF_PART + (size_t)4 * 32 * 2048 * 4;
  constexpr size_t OFF_SIN  = OFF_COS + (size_t)2048 * 64 * 4;
  constexpr size_t SZ_PERM  = (size_t)2048 * 2048 * 2;             // 8MB
  constexpr size_t OFF_A    = OFF_SIN + (size_t)2048 * 64 * 4;     // 48MB region
  constexpr size_t OFF_PTQH = OFF_A;
  constexpr size_t OFF_PTQL = OFF_PTQH + SZ_PERM;
  constexpr size_t OFF_PTOH = OFF_PTQL + SZ_PERM;
  constexpr size_t OFF_PTOL = OFF_PTOH + SZ_PERM;
  constexpr size_t OFF_PBQ  = OFF_PTOL + SZ_PERM;
  constexpr size_t OFF_PBO  = OFF_PBQ + SZ_PERM;
  constexpr size_t SZ_M8    = (size_t)8192 * 2048 * 2;             // 32MB
  constexpr size_t OFF_B    = OFF_PBO + SZ_PERM;   // mhi   (later: yqkv spans B..C)
  constexpr size_t OFF_C    = OFF_B + SZ_M8;       // mlo
  constexpr size_t OFF_D    = OFF_C + SZ_M8;       // hard  (later: xbf @+0, att @+16MB)
  constexpr size_t OFF_E    = OFF_D + SZ_M8;       // wfin
  // END = OFF_E + SZ_M8 = 186,712,064 bytes

  float* rowsums = (float*)(ws + OFF_ROWS);
  float* colsums = (float*)(ws + OFF_COLS);
  float* part    = (float*)(ws + OFF_PART);
  float* cost    = (float*)(ws + OFF_COS);
  float* sint    = (float*)(ws + OFF_SIN);
  unsigned short* ptqh = (unsigned short*)(ws + OFF_PTQH);
  unsigned short* ptql = (unsigned short*)(ws + OFF_PTQL);
  unsigned short* ptoh = (unsigned short*)(ws + OFF_PTOH);
  unsigned short* ptol = (unsigned short*)(ws + OFF_PTOL);
  unsigned short* pbq  = (unsigned short*)(ws + OFF_PBQ);
  unsigned short* pbo  = (unsigned short*)(ws + OFF_PBO);
  unsigned short* mhi  = (unsigned short*)(ws + OFF_B);
  unsigned short* mlo  = (unsigned short*)(ws + OFF_C);
  unsigned short* hard = (unsigned short*)(ws + OFF_D);
  unsigned short* wfin = (unsigned short*)(ws + OFF_E);
  // aliases (lifetimes verified stage-by-stage):
  unsigned short* yqkv = (unsigned short*)(ws + OFF_B);            // 48MB of B..C
  unsigned short* qhb  = (unsigned short*)(ws + OFF_A);            // 16MB
  unsigned short* khb  = (unsigned short*)(ws + OFF_A + 2 * SZ_PERM);
  unsigned short* vtg  = (unsigned short*)(ws + OFF_A + 4 * SZ_PERM);
  unsigned short* xbf  = (unsigned short*)(ws + OFF_D);            // 16MB
  unsigned short* att  = (unsigned short*)(ws + OFF_D + SZ_M8 / 2);

  Ptr4 Wptrs{{Wq, Wk, Wv, Wo}};
  Ptr4 Sptrs{{sq, sk, sv, so}};
  Ptr4 BiasP{{bq, bk, bv, nullptr}};
  Ptr4 NoAux{{nullptr, nullptr, nullptr, nullptr}};
  constexpr int NOSW = 1 << 30;

  // 1) |W| sums
  k_rowsum<<<dim3(2048, 4), 256, 0, stream>>>(Wptrs, rowsums);
  k_colsum_part<<<dim3(8, 32, 4), 256, 0, stream>>>(Wptrs, part);
  k_colsum_red<<<32, 256, 0, stream>>>(part, colsums);
  // 2) metric (hi/lo split) for all 4 mats, stacked [8192][2048]
  k_metric<<<16384, 256, 0, stream>>>(Wptrs, Sptrs, rowsums, colsums, mhi, mlo);
  // 3) perm prep: transposed hi/lo split + fused plain bf16 cast
  k_perm_prep<<<dim3(32, 32, 2), 256, 0, stream>>>(permq, permo, ptqh, ptql, ptoh, ptol, pbq, pbo);
  // 4) hard = top2of4(metric @ perm)  — merged qkv+o launch, B switch at row 6144
  //    (BK=64 single-buf, 2 barriers/64-K; no XCD swizzle)
  gemm_bt<3, 1, 0><<<dim3(16, 64), 256, 0, stream>>>(mhi, mlo, ptqh, ptql, ptoh, ptol, 6144,
                                                     nullptr, hard, NoAux, 8192, 2048, 2048);
  // 5) Wfinal = W * (hard @ perm^T) — merged, aux p[row>>11] selects Wq..Wo
  gemm_bt<1, 0, 1><<<dim3(16, 64), 256, 0, stream>>>(hard, nullptr, pbq, nullptr, pbo, nullptr, 6144,
                                                     nullptr, wfin, Wptrs, 8192, 2048, 2048);
  // 6) x -> bf16 ; y_qkv = x @ Wfinal^T + bias (bf16, stacked N=6144)
  k_cast_bf<<<4096, 256, 0, stream>>>(hid, xbf);
  gemm_bt<2, 0, 1><<<dim3(48, 32), 256, 0, stream>>>(xbf, nullptr, wfin, nullptr, wfin, nullptr, NOSW,
                                                     nullptr, yqkv, BiasP, 4096, 6144, 2048);
  // 7) RoPE tables, q/k reshape+rope (pair-fused, reads halved), v transpose
  k_rope_tab<<<512, 256, 0, stream>>>(cost, sint);
  k_rope_reshape<<<2048, 256, 0, stream>>>(yqkv, pos, cost, sint, qhb, khb);
  k_vtrans<<<dim3(32, 32), 256, 0, stream>>>(yqkv, vtg);
  // 8) flash attention (paired q-tiles, pipelined K/V loads, XCD swizzle)
  attn_fa<<<dim3(16, 32), 256, 0, stream>>>(qhb, khb, vtg, att);
  // 9) out = attn @ Wo_final^T (f32)
  gemm_bt<0, 0, 1><<<dim3(16, 32), 256, 0, stream>>>(att, nullptr, wfin + (size_t)6144 * 2048, nullptr,
                                                     wfin + (size_t)6144 * 2048, nullptr, NOSW,
                                                     out, nullptr, NoAux, 4096, 2048, 2048);
}